// Round 1
// baseline (527.082 us; speedup 1.0000x reference)
//
#include <hip/hip_runtime.h>

#define S_LEN 2048
#define NH 16
#define HD 64
#define DMODEL 1024
#define NTOK 4096
#define ELTS_PER 4194304  // B*S*D = NTOK*DMODEL

typedef __attribute__((ext_vector_type(8))) __bf16 bfrag;
typedef __attribute__((ext_vector_type(4))) float f32x4;

__device__ inline float bf2f(short s) {
  unsigned int u = ((unsigned int)(unsigned short)s) << 16;
  float f;
  __builtin_memcpy(&f, &u, 4);
  return f;
}
__device__ inline short f2bf(float f) {
  unsigned int u;
  __builtin_memcpy(&u, &f, 4);
  u = (u + 0x7fffu + ((u >> 16) & 1u)) >> 16;
  return (short)u;
}

// ---------------- convert x: f32 -> bf16 ----------------
__global__ __launch_bounds__(256) void cvt_bf16_kernel(const float* __restrict__ in,
                                                       short* __restrict__ out, int n) {
  int i = (blockIdx.x * 256 + threadIdx.x) * 4;
  if (i + 3 < n) {
    float4 v = *reinterpret_cast<const float4*>(in + i);
    short4 o;
    o.x = f2bf(v.x); o.y = f2bf(v.y); o.z = f2bf(v.z); o.w = f2bf(v.w);
    *reinterpret_cast<short4*>(out + i) = o;
  }
}

// ---------------- transpose + convert weights: f32 [K][N] -> bf16 [N][K] ----------------
__global__ void transpose_cvt(const float* __restrict__ in, short* __restrict__ out,
                              int K, int N) {
  __shared__ float tile[32][33];
  int nb = blockIdx.x * 32, kb = blockIdx.y * 32;
  int tx = threadIdx.x, ty = threadIdx.y;  // block (32,8)
  for (int j = 0; j < 32; j += 8)
    tile[ty + j][tx] = in[(size_t)(kb + ty + j) * N + nb + tx];
  __syncthreads();
  for (int j = 0; j < 32; j += 8)
    out[(size_t)(nb + ty + j) * K + kb + tx] = f2bf(tile[tx][ty + j]);
}

// ---------------- GEMM: C[M,N] = A[M,K] @ B^T[N,K]^T + bias ----------------
// MODE 0: N=6144, scatter bf16 into per-head QKV buffers (6 x [B,H,S,HD])
// MODE 1: N=1024, f32 output [M,1024] + bias
template <int MODE>
__global__ __launch_bounds__(256) void gemm_kernel(
    const short* __restrict__ A0, const short* __restrict__ A1, int lda, int ksplit, int K,
    const short* __restrict__ B0, const short* __restrict__ B1, const short* __restrict__ B2,
    const short* __restrict__ B3, const short* __restrict__ B4, const short* __restrict__ B5,
    const float* __restrict__ bias0, const float* __restrict__ bias1,
    const float* __restrict__ bias2, const float* __restrict__ bias3,
    const float* __restrict__ bias4, const float* __restrict__ bias5,
    float* __restrict__ outF, short* __restrict__ outQ) {
  __shared__ short As[128 * 40];  // rows padded to 40 elems (80 B): 16B-aligned, ~2-way banks
  __shared__ short Bs[128 * 40];
  const int tid = threadIdx.x;
  const int n0 = blockIdx.x * 128;
  const int m0 = blockIdx.y * 128;
  const short* Bp[6] = {B0, B1, B2, B3, B4, B5};
  const float* biasP[6] = {bias0, bias1, bias2, bias3, bias4, bias5};
  const int nsel = n0 >> 10;
  const short* Bt = Bp[nsel] + (size_t)(n0 & 1023) * K;
  const float* bsel = biasP[nsel];

  const int sr = tid >> 2;          // staging row 0..63 (+64)
  const int sc = (tid & 3) * 8;     // staging col
  const int lane = tid & 63;
  const int w = tid >> 6;
  const int wm = (w >> 1) * 64;
  const int wn = (w & 1) * 64;
  const int lr = lane & 15;
  const int lg = lane >> 4;

  f32x4 acc[4][4];
  for (int a = 0; a < 4; ++a)
    for (int b = 0; b < 4; ++b) acc[a][b] = {0.f, 0.f, 0.f, 0.f};

  for (int k0 = 0; k0 < K; k0 += 32) {
    const short* Abase;
    int kc;
    if (k0 < ksplit) { Abase = A0; kc = k0; } else { Abase = A1; kc = k0 - ksplit; }
    __syncthreads();
    for (int p = 0; p < 2; ++p) {
      int row = sr + p * 64;
      *reinterpret_cast<uint4*>(&As[row * 40 + sc]) =
          *reinterpret_cast<const uint4*>(Abase + (size_t)(m0 + row) * lda + kc + sc);
      *reinterpret_cast<uint4*>(&Bs[row * 40 + sc]) =
          *reinterpret_cast<const uint4*>(Bt + (size_t)row * K + k0 + sc);
    }
    __syncthreads();
    bfrag af[4], bfr[4];
    for (int t = 0; t < 4; ++t) {
      af[t] = *reinterpret_cast<const bfrag*>(&As[(wm + t * 16 + lr) * 40 + lg * 8]);
      bfr[t] = *reinterpret_cast<const bfrag*>(&Bs[(wn + t * 16 + lr) * 40 + lg * 8]);
    }
    for (int mt = 0; mt < 4; ++mt)
      for (int nt = 0; nt < 4; ++nt)
        acc[mt][nt] = __builtin_amdgcn_mfma_f32_16x16x32_bf16(af[mt], bfr[nt], acc[mt][nt], 0, 0, 0);
  }

  for (int mt = 0; mt < 4; ++mt)
    for (int nt = 0; nt < 4; ++nt)
      for (int i = 0; i < 4; ++i) {
        int row = m0 + wm + mt * 16 + lg * 4 + i;
        int col = n0 + wn + nt * 16 + lr;
        float v = acc[mt][nt][i];
        if constexpr (MODE == 0) {
          int nh = col & 1023;
          v += bsel[nh];
          int hh = nh >> 6, d = nh & 63;
          int bb = row >> 11, s = row & 2047;
          outQ[(size_t)nsel * ELTS_PER + (((size_t)(bb * NH + hh) * S_LEN + s) * HD) + d] =
              f2bf(v);
        } else {
          v += bias0[col];
          outF[(size_t)row * DMODEL + col] = v;
        }
      }
}

// ---------------- causal flash attention fwd ----------------
__global__ __launch_bounds__(256) void attn_fwd_kernel(const short* __restrict__ Q,
                                                       const short* __restrict__ Kk,
                                                       const short* __restrict__ V,
                                                       short* __restrict__ fwd) {
  __shared__ short Kt[64 * 72];        // K tile row-major, padded
  __shared__ short Vt[64 * 72];        // V tile transposed: Vt[d][k]
  __shared__ short Ps[4][16 * 72];     // per-wave P tile

  const int qb = blockIdx.x;
  const int h = blockIdx.y;
  const int b = blockIdx.z;
  const int tid = threadIdx.x;
  const int lane = tid & 63;
  const int w = tid >> 6;
  const int lr = lane & 15;
  const int lg = lane >> 4;

  const size_t hb = (size_t)(b * NH + h) * S_LEN * HD;
  const int q0 = qb * 64 + w * 16;

  bfrag qf[2];
  for (int c = 0; c < 2; ++c)
    qf[c] = *reinterpret_cast<const bfrag*>(Q + hb + (size_t)(q0 + lr) * HD + c * 32 + lg * 8);

  f32x4 oacc[4];
  for (int i = 0; i < 4; ++i) oacc[i] = {0.f, 0.f, 0.f, 0.f};
  float mrow[4] = {-1e30f, -1e30f, -1e30f, -1e30f};
  float lsum[4] = {0.f, 0.f, 0.f, 0.f};

  const int sr_ = tid >> 3;        // 0..31
  const int sc_ = (tid & 7) * 8;

  for (int kt = 0; kt <= qb; ++kt) {
    __syncthreads();
    for (int p = 0; p < 2; ++p) {
      int row = sr_ + p * 32;
      *reinterpret_cast<uint4*>(&Kt[row * 72 + sc_]) =
          *reinterpret_cast<const uint4*>(Kk + hb + (size_t)(kt * 64 + row) * HD + sc_);
      uint4 vv = *reinterpret_cast<const uint4*>(V + hb + (size_t)(kt * 64 + row) * HD + sc_);
      const short* vs = reinterpret_cast<const short*>(&vv);
      for (int e = 0; e < 8; ++e) Vt[(sc_ + e) * 72 + row] = vs[e];
    }
    __syncthreads();

    f32x4 sv[4];
    for (int nb = 0; nb < 4; ++nb) {
      bfrag k0f = *reinterpret_cast<const bfrag*>(&Kt[(nb * 16 + lr) * 72 + lg * 8]);
      bfrag k1f = *reinterpret_cast<const bfrag*>(&Kt[(nb * 16 + lr) * 72 + 32 + lg * 8]);
      f32x4 z = {0.f, 0.f, 0.f, 0.f};
      z = __builtin_amdgcn_mfma_f32_16x16x32_bf16(qf[0], k0f, z, 0, 0, 0);
      sv[nb] = __builtin_amdgcn_mfma_f32_16x16x32_bf16(qf[1], k1f, z, 0, 0, 0);
    }
    float mx[4];
    for (int i = 0; i < 4; ++i) {
      int rowg = q0 + lg * 4 + i;
      float m = -1e30f;
      for (int nb = 0; nb < 4; ++nb) {
        int colg = kt * 64 + nb * 16 + lr;
        float t = sv[nb][i] * 0.125f;
        if (colg > rowg) t = -1e30f;
        sv[nb][i] = t;
        m = fmaxf(m, t);
      }
      mx[i] = m;
    }
    for (int off = 1; off < 16; off <<= 1)
      for (int i = 0; i < 4; ++i) mx[i] = fmaxf(mx[i], __shfl_xor(mx[i], off));
    for (int i = 0; i < 4; ++i) {
      float mn = fmaxf(mrow[i], mx[i]);
      float alpha = __expf(mrow[i] - mn);
      mrow[i] = mn;
      lsum[i] *= alpha;
      for (int nd = 0; nd < 4; ++nd) oacc[nd][i] *= alpha;
    }
    short* Pw = Ps[w];
    float rs[4] = {0.f, 0.f, 0.f, 0.f};
    for (int nb = 0; nb < 4; ++nb)
      for (int i = 0; i < 4; ++i) {
        float p = __expf(sv[nb][i] - mrow[i]);
        rs[i] += p;
        Pw[(lg * 4 + i) * 72 + nb * 16 + lr] = f2bf(p);
      }
    for (int off = 1; off < 16; off <<= 1)
      for (int i = 0; i < 4; ++i) rs[i] += __shfl_xor(rs[i], off);
    for (int i = 0; i < 4; ++i) lsum[i] += rs[i];

    for (int kc = 0; kc < 2; ++kc) {
      bfrag pa = *reinterpret_cast<const bfrag*>(&Pw[lr * 72 + kc * 32 + lg * 8]);
      for (int nd = 0; nd < 4; ++nd) {
        bfrag vb = *reinterpret_cast<const bfrag*>(&Vt[(nd * 16 + lr) * 72 + kc * 32 + lg * 8]);
        oacc[nd] = __builtin_amdgcn_mfma_f32_16x16x32_bf16(pa, vb, oacc[nd], 0, 0, 0);
      }
    }
  }

  for (int nd = 0; nd < 4; ++nd)
    for (int i = 0; i < 4; ++i) {
      int rowg = q0 + lg * 4 + i;
      float ov = oacc[nd][i] / lsum[i];
      fwd[(size_t)(b * S_LEN + rowg) * DMODEL + h * HD + nd * 16 + lr] = f2bf(ov);
    }
}

// ---------------- windowed backward attention ----------------
__global__ __launch_bounds__(256) void attn_bwd_kernel(const short* __restrict__ Qb,
                                                       const short* __restrict__ Kb,
                                                       const short* __restrict__ Vb,
                                                       short* __restrict__ bwd) {
  const int tid = threadIdx.x;
  const int lane = tid & 63;
  const int wg = blockIdx.x * 4 + (tid >> 6);
  const int i = wg & (S_LEN - 1);
  const int h = (wg >> 11) & (NH - 1);
  const int b = wg >> 15;
  const size_t hb = (size_t)(b * NH + h) * S_LEN * HD;
  float o;
  if (i == S_LEN - 1) {
    // reference: all-masked row -> scores reset to 0 -> uniform softmax over ALL keys
    float s = 0.f;
    for (int k = 0; k < S_LEN; ++k) s += bf2f(Vb[hb + (size_t)k * HD + lane]);
    o = s * (1.f / S_LEN);
  } else {
    int jmax = min(32, S_LEN - 1 - i);
    float sc = -1e30f;
    if (lane < jmax) {
      const short* qrow = Qb + hb + (size_t)i * HD;
      const short* krow = Kb + hb + (size_t)(i + 1 + lane) * HD;
      float acc = 0.f;
      for (int e = 0; e < HD; ++e) acc += bf2f(qrow[e]) * bf2f(krow[e]);
      sc = acc * 0.125f;
    }
    float m = sc;
    for (int off = 1; off < 64; off <<= 1) m = fmaxf(m, __shfl_xor(m, off));
    float p = (lane < jmax) ? __expf(sc - m) : 0.f;
    float den = p;
    for (int off = 1; off < 64; off <<= 1) den += __shfl_xor(den, off);
    float oa = 0.f;
    for (int j = 0; j < jmax; ++j) {
      float pj = __shfl(p, j);
      oa += pj * bf2f(Vb[hb + (size_t)(i + 1 + j) * HD + lane]);
    }
    o = oa / den;
  }
  bwd[(size_t)(b * S_LEN + i) * DMODEL + h * HD + lane] = f2bf(o);
}

// ---------------- gate LN + sigmoid + fuse ----------------
__global__ __launch_bounds__(256) void ln_gate_fuse_kernel(
    const float* __restrict__ glin, const float* __restrict__ gln_g,
    const float* __restrict__ gln_b, const short* __restrict__ fwd,
    const short* __restrict__ bwd, const float* __restrict__ bstr,
    short* __restrict__ fused) {
  __shared__ float red[8];
  const int row = blockIdx.x;
  const int tid = threadIdx.x;
  const int lane = tid & 63;
  const int w = tid >> 6;
  float4 x = *reinterpret_cast<const float4*>(glin + (size_t)row * DMODEL + tid * 4);
  float xa[4] = {x.x, x.y, x.z, x.w};
  float s = xa[0] + xa[1] + xa[2] + xa[3];
  float ss = xa[0] * xa[0] + xa[1] * xa[1] + xa[2] * xa[2] + xa[3] * xa[3];
  for (int off = 1; off < 64; off <<= 1) {
    s += __shfl_xor(s, off);
    ss += __shfl_xor(ss, off);
  }
  if (lane == 0) { red[w] = s; red[4 + w] = ss; }
  __syncthreads();
  s = red[0] + red[1] + red[2] + red[3];
  ss = red[4] + red[5] + red[6] + red[7];
  const float mean = s * (1.f / DMODEL);
  const float var = ss * (1.f / DMODEL) - mean * mean;
  const float rstd = rsqrtf(var + 1e-5f);
  const float strength = 0.3f / (1.f + __expf(-bstr[0]));
  for (int e = 0; e < 4; ++e) {
    int idx = tid * 4 + e;
    float g = (xa[e] - mean) * rstd * gln_g[idx] + gln_b[idx];
    float gate = 1.f / (1.f + __expf(-g));
    float f = bf2f(fwd[(size_t)row * DMODEL + idx]) +
              strength * gate * bf2f(bwd[(size_t)row * DMODEL + idx]);
    fused[(size_t)row * DMODEL + idx] = f2bf(f);
  }
}

// ---------------- final residual LN ----------------
__global__ __launch_bounds__(256) void final_ln_kernel(const float* __restrict__ x,
                                                       const float* __restrict__ outb,
                                                       const float* __restrict__ ln_g,
                                                       const float* __restrict__ ln_b,
                                                       float* __restrict__ y) {
  __shared__ float red[8];
  const int row = blockIdx.x;
  const int tid = threadIdx.x;
  const int lane = tid & 63;
  const int w = tid >> 6;
  float4 xv = *reinterpret_cast<const float4*>(x + (size_t)row * DMODEL + tid * 4);
  float4 ov = *reinterpret_cast<const float4*>(outb + (size_t)row * DMODEL + tid * 4);
  float t[4] = {xv.x + ov.x, xv.y + ov.y, xv.z + ov.z, xv.w + ov.w};
  float s = t[0] + t[1] + t[2] + t[3];
  float ss = t[0] * t[0] + t[1] * t[1] + t[2] * t[2] + t[3] * t[3];
  for (int off = 1; off < 64; off <<= 1) {
    s += __shfl_xor(s, off);
    ss += __shfl_xor(ss, off);
  }
  if (lane == 0) { red[w] = s; red[4 + w] = ss; }
  __syncthreads();
  s = red[0] + red[1] + red[2] + red[3];
  ss = red[4] + red[5] + red[6] + red[7];
  const float mean = s * (1.f / DMODEL);
  const float var = ss * (1.f / DMODEL) - mean * mean;
  const float rstd = rsqrtf(var + 1e-5f);
  for (int e = 0; e < 4; ++e) {
    int idx = tid * 4 + e;
    y[(size_t)row * DMODEL + idx] = (t[e] - mean) * rstd * ln_g[idx] + ln_b[idx];
  }
}

extern "C" void kernel_launch(void* const* d_in, const int* in_sizes, int n_in,
                              void* d_out, int out_size, void* d_ws, size_t ws_size,
                              hipStream_t stream) {
  const float* x = (const float*)d_in[0];
  const float* fq_w = (const float*)d_in[1];
  const float* fq_b = (const float*)d_in[2];
  const float* fk_w = (const float*)d_in[3];
  const float* fk_b = (const float*)d_in[4];
  const float* fv_w = (const float*)d_in[5];
  const float* fv_b = (const float*)d_in[6];
  const float* bq_w = (const float*)d_in[7];
  const float* bq_b = (const float*)d_in[8];
  const float* bk_w = (const float*)d_in[9];
  const float* bk_b = (const float*)d_in[10];
  const float* bv_w = (const float*)d_in[11];
  const float* bv_b = (const float*)d_in[12];
  const float* gate_w = (const float*)d_in[13];
  const float* gate_b = (const float*)d_in[14];
  const float* gln_g = (const float*)d_in[15];
  const float* gln_b = (const float*)d_in[16];
  const float* bstr = (const float*)d_in[17];
  const float* out_w = (const float*)d_in[18];
  const float* out_b = (const float*)d_in[19];
  const float* ln_g = (const float*)d_in[20];
  const float* ln_b = (const float*)d_in[21];

  char* ws = (char*)d_ws;
  const size_t MB = 1u << 20;
  // phase-1 region (reused):
  short* xb = (short*)(ws + 0);                 // 8 MB, dead after QKV GEMM
  short* wT0 = (short*)(ws + 8 * MB);           // 6 x 2 MB, dead after QKV GEMM
  short* wT1 = (short*)(ws + 10 * MB);
  short* wT2 = (short*)(ws + 12 * MB);
  short* wT3 = (short*)(ws + 14 * MB);
  short* wT4 = (short*)(ws + 16 * MB);
  short* wT5 = (short*)(ws + 18 * MB);
  short* gwT = (short*)(ws + 20 * MB);          // 4 MB
  short* owT = (short*)(ws + 24 * MB);          // 2 MB
  short* qkv = (short*)(ws + 26 * MB);          // 6 x 8 MB -> ends at 74 MB
  // reuse after the producers are done:
  short* fwd = (short*)(ws + 0);                // 8 MB (over xb)
  short* bwdb = (short*)(ws + 8 * MB);          // 8 MB (over wT0..3)
  float* glin = (float*)(ws + 26 * MB);         // 16 MB (over Q,K)
  short* fused = (short*)(ws + 42 * MB);        // 8 MB (over V)
  float* outb = (float*)(ws + 50 * MB);         // 16 MB (over Qb,Kb)

  dim3 tb(32, 8);
  cvt_bf16_kernel<<<4096, 256, 0, stream>>>(x, xb, ELTS_PER);
  transpose_cvt<<<dim3(32, 32), tb, 0, stream>>>(fq_w, wT0, 1024, 1024);
  transpose_cvt<<<dim3(32, 32), tb, 0, stream>>>(fk_w, wT1, 1024, 1024);
  transpose_cvt<<<dim3(32, 32), tb, 0, stream>>>(fv_w, wT2, 1024, 1024);
  transpose_cvt<<<dim3(32, 32), tb, 0, stream>>>(bq_w, wT3, 1024, 1024);
  transpose_cvt<<<dim3(32, 32), tb, 0, stream>>>(bk_w, wT4, 1024, 1024);
  transpose_cvt<<<dim3(32, 32), tb, 0, stream>>>(bv_w, wT5, 1024, 1024);
  transpose_cvt<<<dim3(32, 64), tb, 0, stream>>>(gate_w, gwT, 2048, 1024);
  transpose_cvt<<<dim3(32, 32), tb, 0, stream>>>(out_w, owT, 1024, 1024);

  // QKV projections: [4096,1024] @ 6x[1024,1024] -> per-head bf16 Q,K,V,Qb,Kb,Vb
  gemm_kernel<0><<<dim3(48, 32), 256, 0, stream>>>(
      xb, xb, 1024, 1024, 1024, wT0, wT1, wT2, wT3, wT4, wT5,
      fq_b, fk_b, fv_b, bq_b, bk_b, bv_b, nullptr, qkv);

  attn_fwd_kernel<<<dim3(32, 16, 2), 256, 0, stream>>>(
      qkv, qkv + (size_t)ELTS_PER, qkv + 2 * (size_t)ELTS_PER, fwd);
  attn_bwd_kernel<<<16384, 256, 0, stream>>>(
      qkv + 3 * (size_t)ELTS_PER, qkv + 4 * (size_t)ELTS_PER, qkv + 5 * (size_t)ELTS_PER, bwdb);

  // gate GEMM: concat(fwd,bwd) [4096,2048] @ gate_w -> glin f32
  gemm_kernel<1><<<dim3(8, 32), 256, 0, stream>>>(
      fwd, bwdb, 1024, 1024, 2048, gwT, gwT, gwT, gwT, gwT, gwT,
      gate_b, gate_b, gate_b, gate_b, gate_b, gate_b, glin, nullptr);

  ln_gate_fuse_kernel<<<4096, 256, 0, stream>>>(glin, gln_g, gln_b, fwd, bwdb, bstr, fused);

  // out GEMM: fused [4096,1024] @ out_w -> outb f32
  gemm_kernel<1><<<dim3(8, 32), 256, 0, stream>>>(
      fused, fused, 1024, 1024, 1024, owT, owT, owT, owT, owT, owT,
      out_b, out_b, out_b, out_b, out_b, out_b, outb, nullptr);

  final_ln_kernel<<<4096, 256, 0, stream>>>(x, outb, ln_g, ln_b, (float*)d_out);
}

// Round 2
// 479.343 us; speedup vs baseline: 1.0996x; 1.0996x over previous
//
#include <hip/hip_runtime.h>

#define S_LEN 2048
#define NH 16
#define HD 64
#define DMODEL 1024
#define NTOK 4096
#define ELTS_PER 4194304  // B*S*D = NTOK*DMODEL

typedef __attribute__((ext_vector_type(8))) __bf16 bfrag;
typedef __attribute__((ext_vector_type(4))) float f32x4;

__device__ inline float bf2f(short s) {
  unsigned int u = ((unsigned int)(unsigned short)s) << 16;
  float f;
  __builtin_memcpy(&f, &u, 4);
  return f;
}
__device__ inline short f2bf(float f) {
  unsigned int u;
  __builtin_memcpy(&u, &f, 4);
  u = (u + 0x7fffu + ((u >> 16) & 1u)) >> 16;
  return (short)u;
}
__device__ inline float bflo(unsigned int u) {
  unsigned int t = u << 16;
  float f; __builtin_memcpy(&f, &t, 4); return f;
}
__device__ inline float bfhi(unsigned int u) {
  unsigned int t = u & 0xffff0000u;
  float f; __builtin_memcpy(&f, &t, 4); return f;
}

// ---------------- convert x: f32 -> bf16 ----------------
__global__ __launch_bounds__(256) void cvt_bf16_kernel(const float* __restrict__ in,
                                                       short* __restrict__ out, int n) {
  int i = (blockIdx.x * 256 + threadIdx.x) * 4;
  if (i + 3 < n) {
    float4 v = *reinterpret_cast<const float4*>(in + i);
    short4 o;
    o.x = f2bf(v.x); o.y = f2bf(v.y); o.z = f2bf(v.z); o.w = f2bf(v.w);
    *reinterpret_cast<short4*>(out + i) = o;
  }
}

// ---------------- transpose + convert weights: f32 [K][N] -> bf16 [N][K] ----------------
__global__ void transpose_cvt(const float* __restrict__ in, short* __restrict__ out,
                              int K, int N) {
  __shared__ float tile[32][33];
  int nb = blockIdx.x * 32, kb = blockIdx.y * 32;
  int tx = threadIdx.x, ty = threadIdx.y;  // block (32,8)
  for (int j = 0; j < 32; j += 8)
    tile[ty + j][tx] = in[(size_t)(kb + ty + j) * N + nb + tx];
  __syncthreads();
  for (int j = 0; j < 32; j += 8)
    out[(size_t)(nb + ty + j) * K + kb + tx] = f2bf(tile[tx][ty + j]);
}

// ---------------- GEMM: C[M,N] = A[M,K] @ B^T[N,K]^T + bias ----------------
// MODE 0: N=6144, scatter bf16 into per-head QKV buffers. V (nsel==2) is
//         written TRANSPOSED as [b,h,d,s] (short4-packed along s).
// MODE 1: N=1024, f32 output [M,1024] + bias
template <int MODE>
__global__ __launch_bounds__(256) void gemm_kernel(
    const short* __restrict__ A0, const short* __restrict__ A1, int lda, int ksplit, int K,
    const short* __restrict__ B0, const short* __restrict__ B1, const short* __restrict__ B2,
    const short* __restrict__ B3, const short* __restrict__ B4, const short* __restrict__ B5,
    const float* __restrict__ bias0, const float* __restrict__ bias1,
    const float* __restrict__ bias2, const float* __restrict__ bias3,
    const float* __restrict__ bias4, const float* __restrict__ bias5,
    float* __restrict__ outF, short* __restrict__ outQ) {
  __shared__ short As[128 * 40];
  __shared__ short Bs[128 * 40];
  const int tid = threadIdx.x;
  const int n0 = blockIdx.x * 128;
  const int m0 = blockIdx.y * 128;
  const short* Bp[6] = {B0, B1, B2, B3, B4, B5};
  const float* biasP[6] = {bias0, bias1, bias2, bias3, bias4, bias5};
  const int nsel = n0 >> 10;
  const short* Bt = Bp[nsel] + (size_t)(n0 & 1023) * K;
  const float* bsel = biasP[nsel];

  const int sr = tid >> 2;
  const int sc = (tid & 3) * 8;
  const int lane = tid & 63;
  const int w = tid >> 6;
  const int wm = (w >> 1) * 64;
  const int wn = (w & 1) * 64;
  const int lr = lane & 15;
  const int lg = lane >> 4;

  f32x4 acc[4][4];
  for (int a = 0; a < 4; ++a)
    for (int b = 0; b < 4; ++b) acc[a][b] = {0.f, 0.f, 0.f, 0.f};

  for (int k0 = 0; k0 < K; k0 += 32) {
    const short* Abase;
    int kc;
    if (k0 < ksplit) { Abase = A0; kc = k0; } else { Abase = A1; kc = k0 - ksplit; }
    __syncthreads();
    for (int p = 0; p < 2; ++p) {
      int row = sr + p * 64;
      *reinterpret_cast<uint4*>(&As[row * 40 + sc]) =
          *reinterpret_cast<const uint4*>(Abase + (size_t)(m0 + row) * lda + kc + sc);
      *reinterpret_cast<uint4*>(&Bs[row * 40 + sc]) =
          *reinterpret_cast<const uint4*>(Bt + (size_t)row * K + k0 + sc);
    }
    __syncthreads();
    bfrag af[4], bfr[4];
    for (int t = 0; t < 4; ++t) {
      af[t] = *reinterpret_cast<const bfrag*>(&As[(wm + t * 16 + lr) * 40 + lg * 8]);
      bfr[t] = *reinterpret_cast<const bfrag*>(&Bs[(wn + t * 16 + lr) * 40 + lg * 8]);
    }
    for (int mt = 0; mt < 4; ++mt)
      for (int nt = 0; nt < 4; ++nt)
        acc[mt][nt] = __builtin_amdgcn_mfma_f32_16x16x32_bf16(af[mt], bfr[nt], acc[mt][nt], 0, 0, 0);
  }

  for (int mt = 0; mt < 4; ++mt)
    for (int nt = 0; nt < 4; ++nt) {
      if constexpr (MODE == 0) {
        int rowb = m0 + wm + mt * 16 + lg * 4;
        int col = n0 + wn + nt * 16 + lr;
        int nh = col & 1023;
        int hh = nh >> 6, d = nh & 63;
        int bb = rowb >> 11, s0 = rowb & 2047;
        float bv = bsel[nh];
        if (nsel == 2) {
          // V transposed: [b,h,d,s], pack 4 consecutive s
          short4 o;
          o.x = f2bf(acc[mt][nt][0] + bv);
          o.y = f2bf(acc[mt][nt][1] + bv);
          o.z = f2bf(acc[mt][nt][2] + bv);
          o.w = f2bf(acc[mt][nt][3] + bv);
          *reinterpret_cast<short4*>(
              outQ + (size_t)2 * ELTS_PER +
              ((size_t)(bb * NH + hh) * HD + d) * S_LEN + s0) = o;
        } else {
          for (int i = 0; i < 4; ++i) {
            float v = acc[mt][nt][i] + bv;
            outQ[(size_t)nsel * ELTS_PER +
                 (((size_t)(bb * NH + hh) * S_LEN + (s0 + i)) * HD) + d] = f2bf(v);
          }
        }
      } else {
        for (int i = 0; i < 4; ++i) {
          int row = m0 + wm + mt * 16 + lg * 4 + i;
          int col = n0 + wn + nt * 16 + lr;
          outF[(size_t)row * DMODEL + col] = acc[mt][nt][i] + bias0[col];
        }
      }
    }
}

// ---------------- causal flash attention fwd (v2) ----------------
// 32 q-rows per wave, 4 independent waves per block, no barriers.
// K row-major [b,h,s,d]; V transposed [b,h,d,s]. K/V frags straight from
// global (L2-resident: 256 KB/head). Per-wave LDS only for the P round-trip.
__global__ __launch_bounds__(256) void attn_fwd_kernel(const short* __restrict__ Q,
                                                       const short* __restrict__ Kk,
                                                       const short* __restrict__ VT,
                                                       short* __restrict__ fwd) {
  __shared__ short Ps[4][32 * 72];
  const int tid = threadIdx.x;
  const int lane = tid & 63;
  const int w = tid >> 6;
  const int lr = lane & 15;
  const int lg = lane >> 4;
  const int qb = 15 - blockIdx.x;  // heaviest blocks first
  const int h = blockIdx.y;
  const int b = blockIdx.z;
  const size_t hb = (size_t)(b * NH + h) * S_LEN * HD;
  const int q0 = qb * 128 + w * 32;
  short* Pw = Ps[w];

  bfrag qf[2][2];
  for (int mt = 0; mt < 2; ++mt)
    for (int kc = 0; kc < 2; ++kc)
      qf[mt][kc] = *reinterpret_cast<const bfrag*>(
          Q + hb + (size_t)(q0 + mt * 16 + lr) * HD + kc * 32 + lg * 8);

  f32x4 oacc[2][4];
  for (int mt = 0; mt < 2; ++mt)
    for (int nd = 0; nd < 4; ++nd) oacc[mt][nd] = {0.f, 0.f, 0.f, 0.f};
  float mrow[2][4], lsum[2][4];
  for (int mt = 0; mt < 2; ++mt)
    for (int i = 0; i < 4; ++i) { mrow[mt][i] = -1e30f; lsum[mt][i] = 0.f; }

  const int ktmax = (q0 + 31) >> 6;
  for (int kt = 0; kt <= ktmax; ++kt) {
    // --- K frags from global ---
    bfrag kf[4][2];
    for (int nb = 0; nb < 4; ++nb)
      for (int kc = 0; kc < 2; ++kc)
        kf[nb][kc] = *reinterpret_cast<const bfrag*>(
            Kk + hb + (size_t)(kt * 64 + nb * 16 + lr) * HD + kc * 32 + lg * 8);
    // --- QK^T ---
    f32x4 sv[2][4];
    for (int mt = 0; mt < 2; ++mt)
      for (int nb = 0; nb < 4; ++nb) {
        f32x4 z = {0.f, 0.f, 0.f, 0.f};
        z = __builtin_amdgcn_mfma_f32_16x16x32_bf16(qf[mt][0], kf[nb][0], z, 0, 0, 0);
        sv[mt][nb] = __builtin_amdgcn_mfma_f32_16x16x32_bf16(qf[mt][1], kf[nb][1], z, 0, 0, 0);
      }
    // --- scale + mask + row max ---
    float mx[2][4];
    const bool need_mask = (kt * 64 + 63) > q0;
    for (int mt = 0; mt < 2; ++mt)
      for (int i = 0; i < 4; ++i) {
        int rowg = q0 + mt * 16 + lg * 4 + i;
        float m = -1e30f;
        for (int nb = 0; nb < 4; ++nb) {
          float t = sv[mt][nb][i] * 0.125f;
          if (need_mask && (kt * 64 + nb * 16 + lr) > rowg) t = -1e30f;
          sv[mt][nb][i] = t;
          m = fmaxf(m, t);
        }
        mx[mt][i] = m;
      }
    for (int off = 1; off < 16; off <<= 1)
      for (int mt = 0; mt < 2; ++mt)
        for (int i = 0; i < 4; ++i) mx[mt][i] = fmaxf(mx[mt][i], __shfl_xor(mx[mt][i], off));
    // --- online rescale ---
    for (int mt = 0; mt < 2; ++mt)
      for (int i = 0; i < 4; ++i) {
        float mn = fmaxf(mrow[mt][i], mx[mt][i]);
        float alpha = __expf(mrow[mt][i] - mn);
        mrow[mt][i] = mn;
        lsum[mt][i] *= alpha;
        for (int nd = 0; nd < 4; ++nd) oacc[mt][nd][i] *= alpha;
      }
    // --- exp, P write, row sum ---
    float rs[2][4] = {{0.f, 0.f, 0.f, 0.f}, {0.f, 0.f, 0.f, 0.f}};
    for (int mt = 0; mt < 2; ++mt)
      for (int nb = 0; nb < 4; ++nb)
        for (int i = 0; i < 4; ++i) {
          float p = __expf(sv[mt][nb][i] - mrow[mt][i]);
          rs[mt][i] += p;
          Pw[(mt * 16 + lg * 4 + i) * 72 + nb * 16 + lr] = f2bf(p);
        }
    for (int off = 1; off < 16; off <<= 1)
      for (int mt = 0; mt < 2; ++mt)
        for (int i = 0; i < 4; ++i) rs[mt][i] += __shfl_xor(rs[mt][i], off);
    for (int mt = 0; mt < 2; ++mt)
      for (int i = 0; i < 4; ++i) lsum[mt][i] += rs[mt][i];
    // --- V frags from global (transposed layout) + PV ---
    bfrag vf[4][2];
    for (int nd = 0; nd < 4; ++nd)
      for (int kc = 0; kc < 2; ++kc)
        vf[nd][kc] = *reinterpret_cast<const bfrag*>(
            VT + hb + (size_t)(nd * 16 + lr) * S_LEN + kt * 64 + kc * 32 + lg * 8);
    for (int mt = 0; mt < 2; ++mt) {
      bfrag pa0 = *reinterpret_cast<const bfrag*>(&Pw[(mt * 16 + lr) * 72 + lg * 8]);
      bfrag pa1 = *reinterpret_cast<const bfrag*>(&Pw[(mt * 16 + lr) * 72 + 32 + lg * 8]);
      for (int nd = 0; nd < 4; ++nd) {
        oacc[mt][nd] = __builtin_amdgcn_mfma_f32_16x16x32_bf16(pa0, vf[nd][0], oacc[mt][nd], 0, 0, 0);
        oacc[mt][nd] = __builtin_amdgcn_mfma_f32_16x16x32_bf16(pa1, vf[nd][1], oacc[mt][nd], 0, 0, 0);
      }
    }
  }

  for (int mt = 0; mt < 2; ++mt)
    for (int nd = 0; nd < 4; ++nd)
      for (int i = 0; i < 4; ++i) {
        int rowg = q0 + mt * 16 + lg * 4 + i;
        float ov = oacc[mt][nd][i] / lsum[mt][i];
        fwd[(size_t)(b * S_LEN + rowg) * DMODEL + h * HD + nd * 16 + lr] = f2bf(ov);
      }
}

// ---------------- windowed backward attention (v2: vectorized dot) ----------------
__global__ __launch_bounds__(256) void attn_bwd_kernel(const short* __restrict__ Qb,
                                                       const short* __restrict__ Kb,
                                                       const short* __restrict__ Vb,
                                                       short* __restrict__ bwd) {
  const int tid = threadIdx.x;
  const int lane = tid & 63;
  const int wg = blockIdx.x * 4 + (tid >> 6);
  const int i = wg & (S_LEN - 1);
  const int h = (wg >> 11) & (NH - 1);
  const int b = wg >> 15;
  const size_t hb = (size_t)(b * NH + h) * S_LEN * HD;
  float o;
  if (i == S_LEN - 1) {
    // all-masked row -> uniform softmax over ALL keys
    float a0 = 0.f, a1 = 0.f, a2 = 0.f, a3 = 0.f;
    for (int k = 0; k < S_LEN; k += 4) {
      a0 += bf2f(Vb[hb + (size_t)k * HD + lane]);
      a1 += bf2f(Vb[hb + (size_t)(k + 1) * HD + lane]);
      a2 += bf2f(Vb[hb + (size_t)(k + 2) * HD + lane]);
      a3 += bf2f(Vb[hb + (size_t)(k + 3) * HD + lane]);
    }
    o = (a0 + a1 + a2 + a3) * (1.f / S_LEN);
  } else {
    const int jmax = min(32, S_LEN - 1 - i);
    const int j = lane & 31;
    const int half = lane >> 5;
    float part = 0.f;
    if (j < jmax) {
      const short* qr = Qb + hb + (size_t)i * HD;
      const short* kr = Kb + hb + (size_t)(i + 1 + j) * HD;
      for (int c = half * 4; c < half * 4 + 4; ++c) {
        uint4 kv = *reinterpret_cast<const uint4*>(kr + c * 8);
        uint4 qv = *reinterpret_cast<const uint4*>(qr + c * 8);
        part += bflo(kv.x) * bflo(qv.x) + bfhi(kv.x) * bfhi(qv.x);
        part += bflo(kv.y) * bflo(qv.y) + bfhi(kv.y) * bfhi(qv.y);
        part += bflo(kv.z) * bflo(qv.z) + bfhi(kv.z) * bfhi(qv.z);
        part += bflo(kv.w) * bflo(qv.w) + bfhi(kv.w) * bfhi(qv.w);
      }
    }
    part += __shfl_xor(part, 32);
    float sc = (j < jmax) ? part * 0.125f : -1e30f;
    float m = sc;
    for (int off = 1; off < 32; off <<= 1) m = fmaxf(m, __shfl_xor(m, off));
    float p = (j < jmax) ? __expf(sc - m) : 0.f;
    float den = p;
    for (int off = 1; off < 32; off <<= 1) den += __shfl_xor(den, off);
    float oa = 0.f;
    for (int jj = 0; jj < jmax; ++jj) {
      float pj = __shfl(p, jj);
      oa += pj * bf2f(Vb[hb + (size_t)(i + 1 + jj) * HD + lane]);
    }
    o = oa / den;
  }
  bwd[(size_t)(b * S_LEN + i) * DMODEL + h * HD + lane] = f2bf(o);
}

// ---------------- gate LN + sigmoid + fuse ----------------
__global__ __launch_bounds__(256) void ln_gate_fuse_kernel(
    const float* __restrict__ glin, const float* __restrict__ gln_g,
    const float* __restrict__ gln_b, const short* __restrict__ fwd,
    const short* __restrict__ bwd, const float* __restrict__ bstr,
    short* __restrict__ fused) {
  __shared__ float red[8];
  const int row = blockIdx.x;
  const int tid = threadIdx.x;
  const int lane = tid & 63;
  const int w = tid >> 6;
  float4 x = *reinterpret_cast<const float4*>(glin + (size_t)row * DMODEL + tid * 4);
  float xa[4] = {x.x, x.y, x.z, x.w};
  float s = xa[0] + xa[1] + xa[2] + xa[3];
  float ss = xa[0] * xa[0] + xa[1] * xa[1] + xa[2] * xa[2] + xa[3] * xa[3];
  for (int off = 1; off < 64; off <<= 1) {
    s += __shfl_xor(s, off);
    ss += __shfl_xor(ss, off);
  }
  if (lane == 0) { red[w] = s; red[4 + w] = ss; }
  __syncthreads();
  s = red[0] + red[1] + red[2] + red[3];
  ss = red[4] + red[5] + red[6] + red[7];
  const float mean = s * (1.f / DMODEL);
  const float var = ss * (1.f / DMODEL) - mean * mean;
  const float rstd = rsqrtf(var + 1e-5f);
  const float strength = 0.3f / (1.f + __expf(-bstr[0]));
  for (int e = 0; e < 4; ++e) {
    int idx = tid * 4 + e;
    float g = (xa[e] - mean) * rstd * gln_g[idx] + gln_b[idx];
    float gate = 1.f / (1.f + __expf(-g));
    float f = bf2f(fwd[(size_t)row * DMODEL + idx]) +
              strength * gate * bf2f(bwd[(size_t)row * DMODEL + idx]);
    fused[(size_t)row * DMODEL + idx] = f2bf(f);
  }
}

// ---------------- final residual LN ----------------
__global__ __launch_bounds__(256) void final_ln_kernel(const float* __restrict__ x,
                                                       const float* __restrict__ outb,
                                                       const float* __restrict__ ln_g,
                                                       const float* __restrict__ ln_b,
                                                       float* __restrict__ y) {
  __shared__ float red[8];
  const int row = blockIdx.x;
  const int tid = threadIdx.x;
  const int lane = tid & 63;
  const int w = tid >> 6;
  float4 xv = *reinterpret_cast<const float4*>(x + (size_t)row * DMODEL + tid * 4);
  float4 ov = *reinterpret_cast<const float4*>(outb + (size_t)row * DMODEL + tid * 4);
  float t[4] = {xv.x + ov.x, xv.y + ov.y, xv.z + ov.z, xv.w + ov.w};
  float s = t[0] + t[1] + t[2] + t[3];
  float ss = t[0] * t[0] + t[1] * t[1] + t[2] * t[2] + t[3] * t[3];
  for (int off = 1; off < 64; off <<= 1) {
    s += __shfl_xor(s, off);
    ss += __shfl_xor(ss, off);
  }
  if (lane == 0) { red[w] = s; red[4 + w] = ss; }
  __syncthreads();
  s = red[0] + red[1] + red[2] + red[3];
  ss = red[4] + red[5] + red[6] + red[7];
  const float mean = s * (1.f / DMODEL);
  const float var = ss * (1.f / DMODEL) - mean * mean;
  const float rstd = rsqrtf(var + 1e-5f);
  for (int e = 0; e < 4; ++e) {
    int idx = tid * 4 + e;
    y[(size_t)row * DMODEL + idx] = (t[e] - mean) * rstd * ln_g[idx] + ln_b[idx];
  }
}

extern "C" void kernel_launch(void* const* d_in, const int* in_sizes, int n_in,
                              void* d_out, int out_size, void* d_ws, size_t ws_size,
                              hipStream_t stream) {
  const float* x = (const float*)d_in[0];
  const float* fq_w = (const float*)d_in[1];
  const float* fq_b = (const float*)d_in[2];
  const float* fk_w = (const float*)d_in[3];
  const float* fk_b = (const float*)d_in[4];
  const float* fv_w = (const float*)d_in[5];
  const float* fv_b = (const float*)d_in[6];
  const float* bq_w = (const float*)d_in[7];
  const float* bq_b = (const float*)d_in[8];
  const float* bk_w = (const float*)d_in[9];
  const float* bk_b = (const float*)d_in[10];
  const float* bv_w = (const float*)d_in[11];
  const float* bv_b = (const float*)d_in[12];
  const float* gate_w = (const float*)d_in[13];
  const float* gate_b = (const float*)d_in[14];
  const float* gln_g = (const float*)d_in[15];
  const float* gln_b = (const float*)d_in[16];
  const float* bstr = (const float*)d_in[17];
  const float* out_w = (const float*)d_in[18];
  const float* out_b = (const float*)d_in[19];
  const float* ln_g = (const float*)d_in[20];
  const float* ln_b = (const float*)d_in[21];

  char* ws = (char*)d_ws;
  const size_t MB = 1u << 20;
  short* xb = (short*)(ws + 0);
  short* wT0 = (short*)(ws + 8 * MB);
  short* wT1 = (short*)(ws + 10 * MB);
  short* wT2 = (short*)(ws + 12 * MB);
  short* wT3 = (short*)(ws + 14 * MB);
  short* wT4 = (short*)(ws + 16 * MB);
  short* wT5 = (short*)(ws + 18 * MB);
  short* gwT = (short*)(ws + 20 * MB);
  short* owT = (short*)(ws + 24 * MB);
  short* qkv = (short*)(ws + 26 * MB);
  short* fwd = (short*)(ws + 0);
  short* bwdb = (short*)(ws + 8 * MB);
  float* glin = (float*)(ws + 26 * MB);
  short* fused = (short*)(ws + 42 * MB);
  float* outb = (float*)(ws + 50 * MB);

  dim3 tb(32, 8);
  cvt_bf16_kernel<<<4096, 256, 0, stream>>>(x, xb, ELTS_PER);
  transpose_cvt<<<dim3(32, 32), tb, 0, stream>>>(fq_w, wT0, 1024, 1024);
  transpose_cvt<<<dim3(32, 32), tb, 0, stream>>>(fk_w, wT1, 1024, 1024);
  transpose_cvt<<<dim3(32, 32), tb, 0, stream>>>(fv_w, wT2, 1024, 1024);
  transpose_cvt<<<dim3(32, 32), tb, 0, stream>>>(bq_w, wT3, 1024, 1024);
  transpose_cvt<<<dim3(32, 32), tb, 0, stream>>>(bk_w, wT4, 1024, 1024);
  transpose_cvt<<<dim3(32, 32), tb, 0, stream>>>(bv_w, wT5, 1024, 1024);
  transpose_cvt<<<dim3(32, 64), tb, 0, stream>>>(gate_w, gwT, 2048, 1024);
  transpose_cvt<<<dim3(32, 32), tb, 0, stream>>>(out_w, owT, 1024, 1024);

  gemm_kernel<0><<<dim3(48, 32), 256, 0, stream>>>(
      xb, xb, 1024, 1024, 1024, wT0, wT1, wT2, wT3, wT4, wT5,
      fq_b, fk_b, fv_b, bq_b, bk_b, bv_b, nullptr, qkv);

  attn_fwd_kernel<<<dim3(16, 16, 2), 256, 0, stream>>>(
      qkv, qkv + (size_t)ELTS_PER, qkv + 2 * (size_t)ELTS_PER, fwd);
  attn_bwd_kernel<<<16384, 256, 0, stream>>>(
      qkv + 3 * (size_t)ELTS_PER, qkv + 4 * (size_t)ELTS_PER, qkv + 5 * (size_t)ELTS_PER, bwdb);

  gemm_kernel<1><<<dim3(8, 32), 256, 0, stream>>>(
      fwd, bwdb, 1024, 1024, 2048, gwT, gwT, gwT, gwT, gwT, gwT,
      gate_b, gate_b, gate_b, gate_b, gate_b, gate_b, glin, nullptr);

  ln_gate_fuse_kernel<<<4096, 256, 0, stream>>>(glin, gln_g, gln_b, fwd, bwdb, bstr, fused);

  gemm_kernel<1><<<dim3(8, 32), 256, 0, stream>>>(
      fused, fused, 1024, 1024, 1024, owT, owT, owT, owT, owT, owT,
      out_b, out_b, out_b, out_b, out_b, out_b, outb, nullptr);

  final_ln_kernel<<<4096, 256, 0, stream>>>(x, outb, ln_g, ln_b, (float*)d_out);
}

// Round 3
// 370.275 us; speedup vs baseline: 1.4235x; 1.2946x over previous
//
#include <hip/hip_runtime.h>

#define S_LEN 2048
#define NH 16
#define HD 64
#define DMODEL 1024
#define NTOK 4096
#define ELTS_PER 4194304  // B*S*D = NTOK*DMODEL

typedef __attribute__((ext_vector_type(8))) __bf16 bfrag;
typedef __attribute__((ext_vector_type(4))) float f32x4;

__device__ inline float bf2f(short s) {
  unsigned int u = ((unsigned int)(unsigned short)s) << 16;
  float f;
  __builtin_memcpy(&f, &u, 4);
  return f;
}
__device__ inline short f2bf(float f) {
  unsigned int u;
  __builtin_memcpy(&u, &f, 4);
  u = (u + 0x7fffu + ((u >> 16) & 1u)) >> 16;
  return (short)u;
}
__device__ inline float bflo(unsigned int u) {
  unsigned int t = u << 16;
  float f; __builtin_memcpy(&f, &t, 4); return f;
}
__device__ inline float bfhi(unsigned int u) {
  unsigned int t = u & 0xffff0000u;
  float f; __builtin_memcpy(&f, &t, 4); return f;
}

// ---------------- convert x: f32 -> bf16 ----------------
__global__ __launch_bounds__(256) void cvt_bf16_kernel(const float* __restrict__ in,
                                                       short* __restrict__ out, int n) {
  int i = (blockIdx.x * 256 + threadIdx.x) * 4;
  if (i + 3 < n) {
    float4 v = *reinterpret_cast<const float4*>(in + i);
    short4 o;
    o.x = f2bf(v.x); o.y = f2bf(v.y); o.z = f2bf(v.z); o.w = f2bf(v.w);
    *reinterpret_cast<short4*>(out + i) = o;
  }
}

// ---------------- transpose + convert weights: f32 [K][N] -> bf16 [N][K] ----------------
__global__ void transpose_cvt(const float* __restrict__ in, short* __restrict__ out,
                              int K, int N) {
  __shared__ float tile[32][33];
  int nb = blockIdx.x * 32, kb = blockIdx.y * 32;
  int tx = threadIdx.x, ty = threadIdx.y;  // block (32,8)
  for (int j = 0; j < 32; j += 8)
    tile[ty + j][tx] = in[(size_t)(kb + ty + j) * N + nb + tx];
  __syncthreads();
  for (int j = 0; j < 32; j += 8)
    out[(size_t)(nb + ty + j) * K + kb + tx] = f2bf(tile[tx][ty + j]);
}

// ---------------- GEMM: C[M,N] = A[M,K] @ B^T[N,K]^T + bias ----------------
// MODE 0: N=6144, scatter bf16 into per-head QKV buffers. V (nsel==2) and
//         Vb (nsel==5) are written TRANSPOSED as [b,h,d,s] (short4 along s).
// MODE 1: N=1024, f32 output [M,1024] + bias
template <int MODE>
__global__ __launch_bounds__(256) void gemm_kernel(
    const short* __restrict__ A0, const short* __restrict__ A1, int lda, int ksplit, int K,
    const short* __restrict__ B0, const short* __restrict__ B1, const short* __restrict__ B2,
    const short* __restrict__ B3, const short* __restrict__ B4, const short* __restrict__ B5,
    const float* __restrict__ bias0, const float* __restrict__ bias1,
    const float* __restrict__ bias2, const float* __restrict__ bias3,
    const float* __restrict__ bias4, const float* __restrict__ bias5,
    float* __restrict__ outF, short* __restrict__ outQ) {
  __shared__ short As[128 * 40];
  __shared__ short Bs[128 * 40];
  const int tid = threadIdx.x;
  const int n0 = blockIdx.x * 128;
  const int m0 = blockIdx.y * 128;
  const short* Bp[6] = {B0, B1, B2, B3, B4, B5};
  const float* biasP[6] = {bias0, bias1, bias2, bias3, bias4, bias5};
  const int nsel = n0 >> 10;
  const short* Bt = Bp[nsel] + (size_t)(n0 & 1023) * K;
  const float* bsel = biasP[nsel];

  const int sr = tid >> 2;
  const int sc = (tid & 3) * 8;
  const int lane = tid & 63;
  const int w = tid >> 6;
  const int wm = (w >> 1) * 64;
  const int wn = (w & 1) * 64;
  const int lr = lane & 15;
  const int lg = lane >> 4;

  f32x4 acc[4][4];
  for (int a = 0; a < 4; ++a)
    for (int b = 0; b < 4; ++b) acc[a][b] = {0.f, 0.f, 0.f, 0.f};

  for (int k0 = 0; k0 < K; k0 += 32) {
    const short* Abase;
    int kc;
    if (k0 < ksplit) { Abase = A0; kc = k0; } else { Abase = A1; kc = k0 - ksplit; }
    __syncthreads();
    for (int p = 0; p < 2; ++p) {
      int row = sr + p * 64;
      *reinterpret_cast<uint4*>(&As[row * 40 + sc]) =
          *reinterpret_cast<const uint4*>(Abase + (size_t)(m0 + row) * lda + kc + sc);
      *reinterpret_cast<uint4*>(&Bs[row * 40 + sc]) =
          *reinterpret_cast<const uint4*>(Bt + (size_t)row * K + k0 + sc);
    }
    __syncthreads();
    bfrag af[4], bfr[4];
    for (int t = 0; t < 4; ++t) {
      af[t] = *reinterpret_cast<const bfrag*>(&As[(wm + t * 16 + lr) * 40 + lg * 8]);
      bfr[t] = *reinterpret_cast<const bfrag*>(&Bs[(wn + t * 16 + lr) * 40 + lg * 8]);
    }
    for (int mt = 0; mt < 4; ++mt)
      for (int nt = 0; nt < 4; ++nt)
        acc[mt][nt] = __builtin_amdgcn_mfma_f32_16x16x32_bf16(af[mt], bfr[nt], acc[mt][nt], 0, 0, 0);
  }

  for (int mt = 0; mt < 4; ++mt)
    for (int nt = 0; nt < 4; ++nt) {
      if constexpr (MODE == 0) {
        int rowb = m0 + wm + mt * 16 + lg * 4;
        int col = n0 + wn + nt * 16 + lr;
        int nh = col & 1023;
        int hh = nh >> 6, d = nh & 63;
        int bb = rowb >> 11, s0 = rowb & 2047;
        float bv = bsel[nh];
        if (nsel == 2 || nsel == 5) {
          // V / Vb transposed: [b,h,d,s], pack 4 consecutive s
          short4 o;
          o.x = f2bf(acc[mt][nt][0] + bv);
          o.y = f2bf(acc[mt][nt][1] + bv);
          o.z = f2bf(acc[mt][nt][2] + bv);
          o.w = f2bf(acc[mt][nt][3] + bv);
          *reinterpret_cast<short4*>(
              outQ + (size_t)nsel * ELTS_PER +
              ((size_t)(bb * NH + hh) * HD + d) * S_LEN + s0) = o;
        } else {
          for (int i = 0; i < 4; ++i) {
            float v = acc[mt][nt][i] + bv;
            outQ[(size_t)nsel * ELTS_PER +
                 (((size_t)(bb * NH + hh) * S_LEN + (s0 + i)) * HD) + d] = f2bf(v);
          }
        }
      } else {
        for (int i = 0; i < 4; ++i) {
          int row = m0 + wm + mt * 16 + lg * 4 + i;
          int col = n0 + wn + nt * 16 + lr;
          outF[(size_t)row * DMODEL + col] = acc[mt][nt][i] + bias0[col];
        }
      }
    }
}

// ---------------- causal flash attention fwd (v2) ----------------
__global__ __launch_bounds__(256) void attn_fwd_kernel(const short* __restrict__ Q,
                                                       const short* __restrict__ Kk,
                                                       const short* __restrict__ VT,
                                                       short* __restrict__ fwd) {
  __shared__ short Ps[4][32 * 72];
  const int tid = threadIdx.x;
  const int lane = tid & 63;
  const int w = tid >> 6;
  const int lr = lane & 15;
  const int lg = lane >> 4;
  const int qb = 15 - blockIdx.x;  // heaviest blocks first
  const int h = blockIdx.y;
  const int b = blockIdx.z;
  const size_t hb = (size_t)(b * NH + h) * S_LEN * HD;
  const int q0 = qb * 128 + w * 32;
  short* Pw = Ps[w];

  bfrag qf[2][2];
  for (int mt = 0; mt < 2; ++mt)
    for (int kc = 0; kc < 2; ++kc)
      qf[mt][kc] = *reinterpret_cast<const bfrag*>(
          Q + hb + (size_t)(q0 + mt * 16 + lr) * HD + kc * 32 + lg * 8);

  f32x4 oacc[2][4];
  for (int mt = 0; mt < 2; ++mt)
    for (int nd = 0; nd < 4; ++nd) oacc[mt][nd] = {0.f, 0.f, 0.f, 0.f};
  float mrow[2][4], lsum[2][4];
  for (int mt = 0; mt < 2; ++mt)
    for (int i = 0; i < 4; ++i) { mrow[mt][i] = -1e30f; lsum[mt][i] = 0.f; }

  const int ktmax = (q0 + 31) >> 6;
  for (int kt = 0; kt <= ktmax; ++kt) {
    bfrag kf[4][2];
    for (int nb = 0; nb < 4; ++nb)
      for (int kc = 0; kc < 2; ++kc)
        kf[nb][kc] = *reinterpret_cast<const bfrag*>(
            Kk + hb + (size_t)(kt * 64 + nb * 16 + lr) * HD + kc * 32 + lg * 8);
    f32x4 sv[2][4];
    for (int mt = 0; mt < 2; ++mt)
      for (int nb = 0; nb < 4; ++nb) {
        f32x4 z = {0.f, 0.f, 0.f, 0.f};
        z = __builtin_amdgcn_mfma_f32_16x16x32_bf16(qf[mt][0], kf[nb][0], z, 0, 0, 0);
        sv[mt][nb] = __builtin_amdgcn_mfma_f32_16x16x32_bf16(qf[mt][1], kf[nb][1], z, 0, 0, 0);
      }
    float mx[2][4];
    const bool need_mask = (kt * 64 + 63) > q0;
    for (int mt = 0; mt < 2; ++mt)
      for (int i = 0; i < 4; ++i) {
        int rowg = q0 + mt * 16 + lg * 4 + i;
        float m = -1e30f;
        for (int nb = 0; nb < 4; ++nb) {
          float t = sv[mt][nb][i] * 0.125f;
          if (need_mask && (kt * 64 + nb * 16 + lr) > rowg) t = -1e30f;
          sv[mt][nb][i] = t;
          m = fmaxf(m, t);
        }
        mx[mt][i] = m;
      }
    for (int off = 1; off < 16; off <<= 1)
      for (int mt = 0; mt < 2; ++mt)
        for (int i = 0; i < 4; ++i) mx[mt][i] = fmaxf(mx[mt][i], __shfl_xor(mx[mt][i], off));
    for (int mt = 0; mt < 2; ++mt)
      for (int i = 0; i < 4; ++i) {
        float mn = fmaxf(mrow[mt][i], mx[mt][i]);
        float alpha = __expf(mrow[mt][i] - mn);
        mrow[mt][i] = mn;
        lsum[mt][i] *= alpha;
        for (int nd = 0; nd < 4; ++nd) oacc[mt][nd][i] *= alpha;
      }
    float rs[2][4] = {{0.f, 0.f, 0.f, 0.f}, {0.f, 0.f, 0.f, 0.f}};
    for (int mt = 0; mt < 2; ++mt)
      for (int nb = 0; nb < 4; ++nb)
        for (int i = 0; i < 4; ++i) {
          float p = __expf(sv[mt][nb][i] - mrow[mt][i]);
          rs[mt][i] += p;
          Pw[(mt * 16 + lg * 4 + i) * 72 + nb * 16 + lr] = f2bf(p);
        }
    for (int off = 1; off < 16; off <<= 1)
      for (int mt = 0; mt < 2; ++mt)
        for (int i = 0; i < 4; ++i) rs[mt][i] += __shfl_xor(rs[mt][i], off);
    for (int mt = 0; mt < 2; ++mt)
      for (int i = 0; i < 4; ++i) lsum[mt][i] += rs[mt][i];
    bfrag vf[4][2];
    for (int nd = 0; nd < 4; ++nd)
      for (int kc = 0; kc < 2; ++kc)
        vf[nd][kc] = *reinterpret_cast<const bfrag*>(
            VT + hb + (size_t)(nd * 16 + lr) * S_LEN + kt * 64 + kc * 32 + lg * 8);
    for (int mt = 0; mt < 2; ++mt) {
      bfrag pa0 = *reinterpret_cast<const bfrag*>(&Pw[(mt * 16 + lr) * 72 + lg * 8]);
      bfrag pa1 = *reinterpret_cast<const bfrag*>(&Pw[(mt * 16 + lr) * 72 + 32 + lg * 8]);
      for (int nd = 0; nd < 4; ++nd) {
        oacc[mt][nd] = __builtin_amdgcn_mfma_f32_16x16x32_bf16(pa0, vf[nd][0], oacc[mt][nd], 0, 0, 0);
        oacc[mt][nd] = __builtin_amdgcn_mfma_f32_16x16x32_bf16(pa1, vf[nd][1], oacc[mt][nd], 0, 0, 0);
      }
    }
  }

  for (int mt = 0; mt < 2; ++mt)
    for (int nd = 0; nd < 4; ++nd)
      for (int i = 0; i < 4; ++i) {
        int rowg = q0 + mt * 16 + lg * 4 + i;
        float ov = oacc[mt][nd][i] / lsum[mt][i];
        fwd[(size_t)(b * S_LEN + rowg) * DMODEL + h * HD + nd * 16 + lr] = f2bf(ov);
      }
}

// ---------------- windowed backward attention (v3: MFMA single-tile) ----------------
// Wave handles 32 q-rows r0..r0+31; all valid keys live in cols r0..r0+63.
// Q,K frags from global; Vb in transposed [b,h,d,s] layout; P via per-wave LDS.
// Row S-1 (no valid keys) is overwritten afterwards by vmean_kernel.
__global__ __launch_bounds__(256) void attn_bwd_kernel(const short* __restrict__ Qb,
                                                       const short* __restrict__ Kb,
                                                       const short* __restrict__ VT,
                                                       short* __restrict__ bwd) {
  __shared__ short Ps[4][32 * 72];
  const int tid = threadIdx.x;
  const int lane = tid & 63;
  const int w = tid >> 6;
  const int lr = lane & 15;
  const int lg = lane >> 4;
  const int h = blockIdx.y;
  const int b = blockIdx.z;
  const size_t hb = (size_t)(b * NH + h) * S_LEN * HD;
  const int q0 = blockIdx.x * 128 + w * 32;
  short* Pw = Ps[w];

  bfrag qf[2][2];
  for (int mt = 0; mt < 2; ++mt)
    for (int kc = 0; kc < 2; ++kc)
      qf[mt][kc] = *reinterpret_cast<const bfrag*>(
          Qb + hb + (size_t)(q0 + mt * 16 + lr) * HD + kc * 32 + lg * 8);
  bfrag kf[4][2];
  for (int nb = 0; nb < 4; ++nb) {
    int kr = q0 + nb * 16 + lr;
    kr = min(kr, S_LEN - 1);  // clamp loads; masked out logically below
    for (int kc = 0; kc < 2; ++kc)
      kf[nb][kc] = *reinterpret_cast<const bfrag*>(
          Kb + hb + (size_t)kr * HD + kc * 32 + lg * 8);
  }
  f32x4 sv[2][4];
  for (int mt = 0; mt < 2; ++mt)
    for (int nb = 0; nb < 4; ++nb) {
      f32x4 z = {0.f, 0.f, 0.f, 0.f};
      z = __builtin_amdgcn_mfma_f32_16x16x32_bf16(qf[mt][0], kf[nb][0], z, 0, 0, 0);
      sv[mt][nb] = __builtin_amdgcn_mfma_f32_16x16x32_bf16(qf[mt][1], kf[nb][1], z, 0, 0, 0);
    }
  // mask: valid iff col>row && col<=row+32 && col<S ; then row max
  float mx[2][4];
  for (int mt = 0; mt < 2; ++mt)
    for (int i = 0; i < 4; ++i) {
      int rowg = q0 + mt * 16 + lg * 4 + i;
      float m = -1e30f;
      for (int nb = 0; nb < 4; ++nb) {
        int colg = q0 + nb * 16 + lr;
        float t = sv[mt][nb][i] * 0.125f;
        bool valid = (colg > rowg) && (colg <= rowg + 32) && (colg < S_LEN);
        if (!valid) t = -1e30f;
        sv[mt][nb][i] = t;
        m = fmaxf(m, t);
      }
      mx[mt][i] = m;
    }
  for (int off = 1; off < 16; off <<= 1)
    for (int mt = 0; mt < 2; ++mt)
      for (int i = 0; i < 4; ++i) mx[mt][i] = fmaxf(mx[mt][i], __shfl_xor(mx[mt][i], off));
  // exp + P store + row sum (single tile: no online rescale)
  float rs[2][4] = {{0.f, 0.f, 0.f, 0.f}, {0.f, 0.f, 0.f, 0.f}};
  for (int mt = 0; mt < 2; ++mt)
    for (int nb = 0; nb < 4; ++nb)
      for (int i = 0; i < 4; ++i) {
        float p = __expf(sv[mt][nb][i] - mx[mt][i]);
        rs[mt][i] += p;
        Pw[(mt * 16 + lg * 4 + i) * 72 + nb * 16 + lr] = f2bf(p);
      }
  for (int off = 1; off < 16; off <<= 1)
    for (int mt = 0; mt < 2; ++mt)
      for (int i = 0; i < 4; ++i) rs[mt][i] += __shfl_xor(rs[mt][i], off);
  // V frags (transposed layout), clamp s-span into the head
  bfrag vf[4][2];
  for (int nd = 0; nd < 4; ++nd)
    for (int kc = 0; kc < 2; ++kc) {
      int sbase = q0 + kc * 32 + lg * 8;
      sbase = min(sbase, S_LEN - 8);
      vf[nd][kc] = *reinterpret_cast<const bfrag*>(
          VT + hb + (size_t)(nd * 16 + lr) * S_LEN + sbase);
    }
  f32x4 oacc[2][4];
  for (int mt = 0; mt < 2; ++mt)
    for (int nd = 0; nd < 4; ++nd) oacc[mt][nd] = {0.f, 0.f, 0.f, 0.f};
  for (int mt = 0; mt < 2; ++mt) {
    bfrag pa0 = *reinterpret_cast<const bfrag*>(&Pw[(mt * 16 + lr) * 72 + lg * 8]);
    bfrag pa1 = *reinterpret_cast<const bfrag*>(&Pw[(mt * 16 + lr) * 72 + 32 + lg * 8]);
    for (int nd = 0; nd < 4; ++nd) {
      oacc[mt][nd] = __builtin_amdgcn_mfma_f32_16x16x32_bf16(pa0, vf[nd][0], oacc[mt][nd], 0, 0, 0);
      oacc[mt][nd] = __builtin_amdgcn_mfma_f32_16x16x32_bf16(pa1, vf[nd][1], oacc[mt][nd], 0, 0, 0);
    }
  }
  for (int mt = 0; mt < 2; ++mt)
    for (int nd = 0; nd < 4; ++nd)
      for (int i = 0; i < 4; ++i) {
        int rowg = q0 + mt * 16 + lg * 4 + i;
        float ov = oacc[mt][nd][i] / rs[mt][i];
        bwd[(size_t)(b * S_LEN + rowg) * DMODEL + h * HD + nd * 16 + lr] = f2bf(ov);
      }
}

// ---------------- row S-1 of bwd: uniform mean over all Vb keys ----------------
__global__ __launch_bounds__(256) void vmean_kernel(const short* __restrict__ VT,
                                                    short* __restrict__ bwd) {
  __shared__ float red[256];
  const int bh = blockIdx.x;  // b*NH + h
  const int d = threadIdx.x >> 2;
  const int seg = threadIdx.x & 3;
  const short* row = VT + (size_t)bh * S_LEN * HD + (size_t)d * S_LEN + seg * 512;
  float s = 0.f;
  for (int j = 0; j < 512; j += 8) {
    uint4 v = *reinterpret_cast<const uint4*>(row + j);
    s += bflo(v.x) + bfhi(v.x) + bflo(v.y) + bfhi(v.y) +
         bflo(v.z) + bfhi(v.z) + bflo(v.w) + bfhi(v.w);
  }
  red[threadIdx.x] = s;
  __syncthreads();
  if (seg == 0) {
    float t = red[d * 4] + red[d * 4 + 1] + red[d * 4 + 2] + red[d * 4 + 3];
    int b = bh >> 4, h = bh & 15;
    bwd[((size_t)(b * S_LEN + S_LEN - 1)) * DMODEL + h * HD + d] = f2bf(t * (1.f / S_LEN));
  }
}

// ---------------- gate LN + sigmoid + fuse ----------------
__global__ __launch_bounds__(256) void ln_gate_fuse_kernel(
    const float* __restrict__ glin, const float* __restrict__ gln_g,
    const float* __restrict__ gln_b, const short* __restrict__ fwd,
    const short* __restrict__ bwd, const float* __restrict__ bstr,
    short* __restrict__ fused) {
  __shared__ float red[8];
  const int row = blockIdx.x;
  const int tid = threadIdx.x;
  const int lane = tid & 63;
  const int w = tid >> 6;
  float4 x = *reinterpret_cast<const float4*>(glin + (size_t)row * DMODEL + tid * 4);
  float xa[4] = {x.x, x.y, x.z, x.w};
  float s = xa[0] + xa[1] + xa[2] + xa[3];
  float ss = xa[0] * xa[0] + xa[1] * xa[1] + xa[2] * xa[2] + xa[3] * xa[3];
  for (int off = 1; off < 64; off <<= 1) {
    s += __shfl_xor(s, off);
    ss += __shfl_xor(ss, off);
  }
  if (lane == 0) { red[w] = s; red[4 + w] = ss; }
  __syncthreads();
  s = red[0] + red[1] + red[2] + red[3];
  ss = red[4] + red[5] + red[6] + red[7];
  const float mean = s * (1.f / DMODEL);
  const float var = ss * (1.f / DMODEL) - mean * mean;
  const float rstd = rsqrtf(var + 1e-5f);
  const float strength = 0.3f / (1.f + __expf(-bstr[0]));
  for (int e = 0; e < 4; ++e) {
    int idx = tid * 4 + e;
    float g = (xa[e] - mean) * rstd * gln_g[idx] + gln_b[idx];
    float gate = 1.f / (1.f + __expf(-g));
    float f = bf2f(fwd[(size_t)row * DMODEL + idx]) +
              strength * gate * bf2f(bwd[(size_t)row * DMODEL + idx]);
    fused[(size_t)row * DMODEL + idx] = f2bf(f);
  }
}

// ---------------- final residual LN ----------------
__global__ __launch_bounds__(256) void final_ln_kernel(const float* __restrict__ x,
                                                       const float* __restrict__ outb,
                                                       const float* __restrict__ ln_g,
                                                       const float* __restrict__ ln_b,
                                                       float* __restrict__ y) {
  __shared__ float red[8];
  const int row = blockIdx.x;
  const int tid = threadIdx.x;
  const int lane = tid & 63;
  const int w = tid >> 6;
  float4 xv = *reinterpret_cast<const float4*>(x + (size_t)row * DMODEL + tid * 4);
  float4 ov = *reinterpret_cast<const float4*>(outb + (size_t)row * DMODEL + tid * 4);
  float t[4] = {xv.x + ov.x, xv.y + ov.y, xv.z + ov.z, xv.w + ov.w};
  float s = t[0] + t[1] + t[2] + t[3];
  float ss = t[0] * t[0] + t[1] * t[1] + t[2] * t[2] + t[3] * t[3];
  for (int off = 1; off < 64; off <<= 1) {
    s += __shfl_xor(s, off);
    ss += __shfl_xor(ss, off);
  }
  if (lane == 0) { red[w] = s; red[4 + w] = ss; }
  __syncthreads();
  s = red[0] + red[1] + red[2] + red[3];
  ss = red[4] + red[5] + red[6] + red[7];
  const float mean = s * (1.f / DMODEL);
  const float var = ss * (1.f / DMODEL) - mean * mean;
  const float rstd = rsqrtf(var + 1e-5f);
  for (int e = 0; e < 4; ++e) {
    int idx = tid * 4 + e;
    y[(size_t)row * DMODEL + idx] = (t[e] - mean) * rstd * ln_g[idx] + ln_b[idx];
  }
}

extern "C" void kernel_launch(void* const* d_in, const int* in_sizes, int n_in,
                              void* d_out, int out_size, void* d_ws, size_t ws_size,
                              hipStream_t stream) {
  const float* x = (const float*)d_in[0];
  const float* fq_w = (const float*)d_in[1];
  const float* fq_b = (const float*)d_in[2];
  const float* fk_w = (const float*)d_in[3];
  const float* fk_b = (const float*)d_in[4];
  const float* fv_w = (const float*)d_in[5];
  const float* fv_b = (const float*)d_in[6];
  const float* bq_w = (const float*)d_in[7];
  const float* bq_b = (const float*)d_in[8];
  const float* bk_w = (const float*)d_in[9];
  const float* bk_b = (const float*)d_in[10];
  const float* bv_w = (const float*)d_in[11];
  const float* bv_b = (const float*)d_in[12];
  const float* gate_w = (const float*)d_in[13];
  const float* gate_b = (const float*)d_in[14];
  const float* gln_g = (const float*)d_in[15];
  const float* gln_b = (const float*)d_in[16];
  const float* bstr = (const float*)d_in[17];
  const float* out_w = (const float*)d_in[18];
  const float* out_b = (const float*)d_in[19];
  const float* ln_g = (const float*)d_in[20];
  const float* ln_b = (const float*)d_in[21];

  char* ws = (char*)d_ws;
  const size_t MB = 1u << 20;
  short* xb = (short*)(ws + 0);
  short* wT0 = (short*)(ws + 8 * MB);
  short* wT1 = (short*)(ws + 10 * MB);
  short* wT2 = (short*)(ws + 12 * MB);
  short* wT3 = (short*)(ws + 14 * MB);
  short* wT4 = (short*)(ws + 16 * MB);
  short* wT5 = (short*)(ws + 18 * MB);
  short* gwT = (short*)(ws + 20 * MB);
  short* owT = (short*)(ws + 24 * MB);
  short* qkv = (short*)(ws + 26 * MB);
  short* fwd = (short*)(ws + 0);
  short* bwdb = (short*)(ws + 8 * MB);
  float* glin = (float*)(ws + 26 * MB);
  short* fused = (short*)(ws + 42 * MB);
  float* outb = (float*)(ws + 50 * MB);

  dim3 tb(32, 8);
  cvt_bf16_kernel<<<4096, 256, 0, stream>>>(x, xb, ELTS_PER);
  transpose_cvt<<<dim3(32, 32), tb, 0, stream>>>(fq_w, wT0, 1024, 1024);
  transpose_cvt<<<dim3(32, 32), tb, 0, stream>>>(fk_w, wT1, 1024, 1024);
  transpose_cvt<<<dim3(32, 32), tb, 0, stream>>>(fv_w, wT2, 1024, 1024);
  transpose_cvt<<<dim3(32, 32), tb, 0, stream>>>(bq_w, wT3, 1024, 1024);
  transpose_cvt<<<dim3(32, 32), tb, 0, stream>>>(bk_w, wT4, 1024, 1024);
  transpose_cvt<<<dim3(32, 32), tb, 0, stream>>>(bv_w, wT5, 1024, 1024);
  transpose_cvt<<<dim3(32, 64), tb, 0, stream>>>(gate_w, gwT, 2048, 1024);
  transpose_cvt<<<dim3(32, 32), tb, 0, stream>>>(out_w, owT, 1024, 1024);

  gemm_kernel<0><<<dim3(48, 32), 256, 0, stream>>>(
      xb, xb, 1024, 1024, 1024, wT0, wT1, wT2, wT3, wT4, wT5,
      fq_b, fk_b, fv_b, bq_b, bk_b, bv_b, nullptr, qkv);

  attn_fwd_kernel<<<dim3(16, 16, 2), 256, 0, stream>>>(
      qkv, qkv + (size_t)ELTS_PER, qkv + 2 * (size_t)ELTS_PER, fwd);
  attn_bwd_kernel<<<dim3(16, 16, 2), 256, 0, stream>>>(
      qkv + 3 * (size_t)ELTS_PER, qkv + 4 * (size_t)ELTS_PER, qkv + 5 * (size_t)ELTS_PER, bwdb);
  vmean_kernel<<<32, 256, 0, stream>>>(qkv + 5 * (size_t)ELTS_PER, bwdb);

  gemm_kernel<1><<<dim3(8, 32), 256, 0, stream>>>(
      fwd, bwdb, 1024, 1024, 2048, gwT, gwT, gwT, gwT, gwT, gwT,
      gate_b, gate_b, gate_b, gate_b, gate_b, gate_b, glin, nullptr);

  ln_gate_fuse_kernel<<<4096, 256, 0, stream>>>(glin, gln_g, gln_b, fwd, bwdb, bstr, fused);

  gemm_kernel<1><<<dim3(8, 32), 256, 0, stream>>>(
      fused, fused, 1024, 1024, 1024, owT, owT, owT, owT, owT, owT,
      out_b, out_b, out_b, out_b, out_b, out_b, outb, nullptr);

  final_ln_kernel<<<4096, 256, 0, stream>>>(x, outb, ln_g, ln_b, (float*)d_out);
}

// Round 4
// 341.228 us; speedup vs baseline: 1.5447x; 1.0851x over previous
//
#include <hip/hip_runtime.h>

#define S_LEN 2048
#define NH 16
#define HD 64
#define DMODEL 1024
#define NTOK 4096
#define ELTS_PER 4194304  // B*S*D = NTOK*DMODEL
#define QSCALE 0.18033688f  // 0.125 * log2(e), folded into Q/Qb projections

typedef __attribute__((ext_vector_type(8))) __bf16 bfrag;
typedef __attribute__((ext_vector_type(8))) short s8v;
typedef __attribute__((ext_vector_type(4))) float f32x4;

__device__ inline float bf2f(short s) {
  unsigned int u = ((unsigned int)(unsigned short)s) << 16;
  float f;
  __builtin_memcpy(&f, &u, 4);
  return f;
}
__device__ inline short f2bf(float f) {
  unsigned int u;
  __builtin_memcpy(&u, &f, 4);
  u = (u + 0x7fffu + ((u >> 16) & 1u)) >> 16;
  return (short)u;
}
__device__ inline short f2bf_n(float f) {  // native convert (compiler picks cvt_pk)
  __bf16 h = (__bf16)f;
  short s;
  __builtin_memcpy(&s, &h, 2);
  return s;
}
__device__ inline float bflo(unsigned int u) {
  unsigned int t = u << 16;
  float f; __builtin_memcpy(&f, &t, 4); return f;
}
__device__ inline float bfhi(unsigned int u) {
  unsigned int t = u & 0xffff0000u;
  float f; __builtin_memcpy(&f, &t, 4); return f;
}
// async global -> LDS, 16B per lane (dest = wave-uniform base + lane*16)
__device__ __forceinline__ void gll16(const short* g, short* l) {
  __builtin_amdgcn_global_load_lds(
      (const __attribute__((address_space(1))) void*)g,
      (__attribute__((address_space(3))) void*)l, 16, 0, 0);
}

// ---------------- convert x: f32 -> bf16 ----------------
__global__ __launch_bounds__(256) void cvt_bf16_kernel(const float* __restrict__ in,
                                                       short* __restrict__ out, int n) {
  int i = (blockIdx.x * 256 + threadIdx.x) * 4;
  if (i + 3 < n) {
    float4 v = *reinterpret_cast<const float4*>(in + i);
    short4 o;
    o.x = f2bf(v.x); o.y = f2bf(v.y); o.z = f2bf(v.z); o.w = f2bf(v.w);
    *reinterpret_cast<short4*>(out + i) = o;
  }
}

// ---------- transpose + convert ALL weights: f32 [K][N=1024] -> bf16 [N][K] ----------
__global__ void transpose_cvt_all(const float* __restrict__ s0, const float* __restrict__ s1,
                                  const float* __restrict__ s2, const float* __restrict__ s3,
                                  const float* __restrict__ s4, const float* __restrict__ s5,
                                  const float* __restrict__ s6, const float* __restrict__ s7,
                                  short* d0, short* d1, short* d2, short* d3,
                                  short* d4, short* d5, short* d6, short* d7) {
  const int z = blockIdx.z;
  const int K = (z == 7) ? 2048 : 1024;
  if (blockIdx.y * 32 >= K) return;
  const float* srcs[8] = {s0, s1, s2, s3, s4, s5, s6, s7};
  short* dsts[8] = {d0, d1, d2, d3, d4, d5, d6, d7};
  const float* in = srcs[z];
  short* out = dsts[z];
  __shared__ float tile[32][33];
  int nb = blockIdx.x * 32, kb = blockIdx.y * 32;
  int tx = threadIdx.x, ty = threadIdx.y;  // block (32,8)
  for (int j = 0; j < 32; j += 8)
    tile[ty + j][tx] = in[(size_t)(kb + ty + j) * 1024 + nb + tx];
  __syncthreads();
  for (int j = 0; j < 32; j += 8)
    out[(size_t)(nb + ty + j) * K + kb + tx] = f2bf(tile[tx][ty + j]);
}

// ---------------- GEMM: C[M,N] = A[M,K] @ B^T[N,K]^T + bias ----------------
// global_load_lds staging into linear LDS [128][32].
// MODE 0: N=6144, scatter bf16 into per-head QKV buffers. V (nsel==2) and
//         Vb (nsel==5) written TRANSPOSED [b,h,d,s]; Q (0) and Qb (3) scaled by QSCALE.
// MODE 1: N=1024, f32 output [M,1024] + bias
template <int MODE>
__global__ __launch_bounds__(256) void gemm_kernel(
    const short* __restrict__ A0, const short* __restrict__ A1, int lda, int ksplit, int K,
    const short* __restrict__ B0, const short* __restrict__ B1, const short* __restrict__ B2,
    const short* __restrict__ B3, const short* __restrict__ B4, const short* __restrict__ B5,
    const float* __restrict__ bias0, const float* __restrict__ bias1,
    const float* __restrict__ bias2, const float* __restrict__ bias3,
    const float* __restrict__ bias4, const float* __restrict__ bias5,
    float* __restrict__ outF, short* __restrict__ outQ) {
  __shared__ short As[128 * 32];
  __shared__ short Bs[128 * 32];
  const int tid = threadIdx.x;
  const int n0 = blockIdx.x * 128;
  const int m0 = blockIdx.y * 128;
  const short* Bp[6] = {B0, B1, B2, B3, B4, B5};
  const float* biasP[6] = {bias0, bias1, bias2, bias3, bias4, bias5};
  const int nsel = n0 >> 10;
  const short* Bt = Bp[nsel] + (size_t)(n0 & 1023) * K;
  const float* bsel = biasP[nsel];

  const int lane = tid & 63;
  const int w = tid >> 6;
  const int wm = (w >> 1) * 64;
  const int wn = (w & 1) * 64;
  const int lr = lane & 15;
  const int lg = lane >> 4;
  const int gr = lane >> 2;        // staging: row within 16-row group
  const int gs = (lane & 3) * 8;   // staging: elem offset (16 B)

  f32x4 acc[4][4];
  for (int a = 0; a < 4; ++a)
    for (int b = 0; b < 4; ++b) acc[a][b] = {0.f, 0.f, 0.f, 0.f};

  for (int k0 = 0; k0 < K; k0 += 32) {
    const short* Abase;
    int kc;
    if (k0 < ksplit) { Abase = A0; kc = k0; } else { Abase = A1; kc = k0 - ksplit; }
    __syncthreads();
    const short* Ag = Abase + (size_t)(m0 + w * 32 + gr) * lda + kc + gs;
    const short* Bg = Bt + (size_t)(w * 32 + gr) * K + k0 + gs;
    gll16(Ag, &As[(w * 32) * 32]);
    gll16(Ag + (size_t)16 * lda, &As[(w * 32 + 16) * 32]);
    gll16(Bg, &Bs[(w * 32) * 32]);
    gll16(Bg + (size_t)16 * K, &Bs[(w * 32 + 16) * 32]);
    __syncthreads();
    bfrag af[4], bfr[4];
    for (int t = 0; t < 4; ++t) {
      af[t] = *reinterpret_cast<const bfrag*>(&As[(wm + t * 16 + lr) * 32 + lg * 8]);
      bfr[t] = *reinterpret_cast<const bfrag*>(&Bs[(wn + t * 16 + lr) * 32 + lg * 8]);
    }
    for (int mt = 0; mt < 4; ++mt)
      for (int nt = 0; nt < 4; ++nt)
        acc[mt][nt] = __builtin_amdgcn_mfma_f32_16x16x32_bf16(af[mt], bfr[nt], acc[mt][nt], 0, 0, 0);
  }

  const float cmul = (MODE == 0 && (nsel == 0 || nsel == 3)) ? QSCALE : 1.0f;
  for (int mt = 0; mt < 4; ++mt)
    for (int nt = 0; nt < 4; ++nt) {
      if constexpr (MODE == 0) {
        int rowb = m0 + wm + mt * 16 + lg * 4;
        int col = n0 + wn + nt * 16 + lr;
        int nh = col & 1023;
        int hh = nh >> 6, d = nh & 63;
        int bb = rowb >> 11, s0 = rowb & 2047;
        float bv = bsel[nh];
        if (nsel == 2 || nsel == 5) {
          short4 o;
          o.x = f2bf(acc[mt][nt][0] + bv);
          o.y = f2bf(acc[mt][nt][1] + bv);
          o.z = f2bf(acc[mt][nt][2] + bv);
          o.w = f2bf(acc[mt][nt][3] + bv);
          *reinterpret_cast<short4*>(
              outQ + (size_t)nsel * ELTS_PER +
              ((size_t)(bb * NH + hh) * HD + d) * S_LEN + s0) = o;
        } else {
          for (int i = 0; i < 4; ++i) {
            float v = (acc[mt][nt][i] + bv) * cmul;
            outQ[(size_t)nsel * ELTS_PER +
                 (((size_t)(bb * NH + hh) * S_LEN + (s0 + i)) * HD) + d] = f2bf(v);
          }
        }
      } else {
        for (int i = 0; i < 4; ++i) {
          int row = m0 + wm + mt * 16 + lg * 4 + i;
          int col = n0 + wn + nt * 16 + lr;
          outF[(size_t)row * DMODEL + col] = acc[mt][nt][i] + bias0[col];
        }
      }
    }
}

// ---------------- causal flash attention fwd (v3) ----------------
// One wave per 16-row q-chunk; scores pre-scaled by QSCALE in Q projection.
// No online max (scores bounded): p = exp2(s); denominator via ones-MFMA.
// Block p holds mirrored chunks {2p, 2p+1, 127-2p, 126-2p} for balance.
__global__ __launch_bounds__(256) void attn_fwd_kernel(const short* __restrict__ Q,
                                                       const short* __restrict__ Kk,
                                                       const short* __restrict__ VT,
                                                       short* __restrict__ fwd) {
  __shared__ short Ps[4][16 * 72];
  const int tid = threadIdx.x;
  const int lane = tid & 63;
  const int w = tid >> 6;
  const int lr = lane & 15;
  const int lg = lane >> 4;
  const int h = blockIdx.y;
  const int b = blockIdx.z;
  const size_t hb = (size_t)(b * NH + h) * S_LEN * HD;
  short* Pw = Ps[w];

  s8v onesi = {0x3F80, 0x3F80, 0x3F80, 0x3F80, 0x3F80, 0x3F80, 0x3F80, 0x3F80};
  bfrag onesv;
  __builtin_memcpy(&onesv, &onesi, 16);

  const int c = (w < 2) ? (2 * blockIdx.x + w) : (127 - 2 * blockIdx.x - (w - 2));
  const int q0 = c * 16;

  bfrag qf[2];
  for (int kc = 0; kc < 2; ++kc)
    qf[kc] = *reinterpret_cast<const bfrag*>(
        Q + hb + (size_t)(q0 + lr) * HD + kc * 32 + lg * 8);

  f32x4 oacc[4];
  for (int nd = 0; nd < 4; ++nd) oacc[nd] = {0.f, 0.f, 0.f, 0.f};
  f32x4 osum = {0.f, 0.f, 0.f, 0.f};

  const int ktm = c >> 2;
  for (int kt = 0; kt <= ktm; ++kt) {
    bfrag kf[4][2];
    for (int nb = 0; nb < 4; ++nb)
      for (int kc = 0; kc < 2; ++kc)
        kf[nb][kc] = *reinterpret_cast<const bfrag*>(
            Kk + hb + (size_t)(kt * 64 + nb * 16 + lr) * HD + kc * 32 + lg * 8);
    f32x4 sv[4];
    for (int nb = 0; nb < 4; ++nb) {
      f32x4 z = {0.f, 0.f, 0.f, 0.f};
      z = __builtin_amdgcn_mfma_f32_16x16x32_bf16(qf[0], kf[nb][0], z, 0, 0, 0);
      sv[nb] = __builtin_amdgcn_mfma_f32_16x16x32_bf16(qf[1], kf[nb][1], z, 0, 0, 0);
    }
    if (kt == ktm) {  // diagonal tile: causal mask
      for (int nb = 0; nb < 4; ++nb)
        for (int i = 0; i < 4; ++i) {
          int colg = kt * 64 + nb * 16 + lr;
          int rowg = q0 + lg * 4 + i;
          if (colg > rowg) sv[nb][i] = -1e30f;
        }
    }
    // p = exp2(s), store bf16 P tile (per-wave LDS, padded stride 72)
    for (int nb = 0; nb < 4; ++nb)
      for (int i = 0; i < 4; ++i)
        Pw[(lg * 4 + i) * 72 + nb * 16 + lr] = f2bf_n(exp2f(sv[nb][i]));
    // V frags (transposed [d][s] layout)
    bfrag vf[4][2];
    for (int nd = 0; nd < 4; ++nd)
      for (int kc = 0; kc < 2; ++kc)
        vf[nd][kc] = *reinterpret_cast<const bfrag*>(
            VT + hb + (size_t)(nd * 16 + lr) * S_LEN + kt * 64 + kc * 32 + lg * 8);
    bfrag pa0 = *reinterpret_cast<const bfrag*>(&Pw[lr * 72 + lg * 8]);
    bfrag pa1 = *reinterpret_cast<const bfrag*>(&Pw[lr * 72 + 32 + lg * 8]);
    for (int nd = 0; nd < 4; ++nd) {
      oacc[nd] = __builtin_amdgcn_mfma_f32_16x16x32_bf16(pa0, vf[nd][0], oacc[nd], 0, 0, 0);
      oacc[nd] = __builtin_amdgcn_mfma_f32_16x16x32_bf16(pa1, vf[nd][1], oacc[nd], 0, 0, 0);
    }
    osum = __builtin_amdgcn_mfma_f32_16x16x32_bf16(pa0, onesv, osum, 0, 0, 0);
    osum = __builtin_amdgcn_mfma_f32_16x16x32_bf16(pa1, onesv, osum, 0, 0, 0);
  }

  for (int i = 0; i < 4; ++i) {
    int rowg = q0 + lg * 4 + i;
    float inv = 1.0f / osum[i];
    for (int nd = 0; nd < 4; ++nd)
      fwd[(size_t)(b * S_LEN + rowg) * DMODEL + h * HD + nd * 16 + lr] =
          f2bf(oacc[nd][i] * inv);
  }
}

// ---------------- windowed backward attention (MFMA single-tile) ----------------
// Qb pre-scaled by QSCALE; exp2 softmax with per-row max (single tile, cheap).
__global__ __launch_bounds__(256) void attn_bwd_kernel(const short* __restrict__ Qb,
                                                       const short* __restrict__ Kb,
                                                       const short* __restrict__ VT,
                                                       short* __restrict__ bwd) {
  __shared__ short Ps[4][32 * 72];
  const int tid = threadIdx.x;
  const int lane = tid & 63;
  const int w = tid >> 6;
  const int lr = lane & 15;
  const int lg = lane >> 4;
  const int h = blockIdx.y;
  const int b = blockIdx.z;
  const size_t hb = (size_t)(b * NH + h) * S_LEN * HD;
  const int q0 = blockIdx.x * 128 + w * 32;
  short* Pw = Ps[w];

  bfrag qf[2][2];
  for (int mt = 0; mt < 2; ++mt)
    for (int kc = 0; kc < 2; ++kc)
      qf[mt][kc] = *reinterpret_cast<const bfrag*>(
          Qb + hb + (size_t)(q0 + mt * 16 + lr) * HD + kc * 32 + lg * 8);
  bfrag kf[4][2];
  for (int nb = 0; nb < 4; ++nb) {
    int kr = q0 + nb * 16 + lr;
    kr = min(kr, S_LEN - 1);
    for (int kc = 0; kc < 2; ++kc)
      kf[nb][kc] = *reinterpret_cast<const bfrag*>(
          Kb + hb + (size_t)kr * HD + kc * 32 + lg * 8);
  }
  f32x4 sv[2][4];
  for (int mt = 0; mt < 2; ++mt)
    for (int nb = 0; nb < 4; ++nb) {
      f32x4 z = {0.f, 0.f, 0.f, 0.f};
      z = __builtin_amdgcn_mfma_f32_16x16x32_bf16(qf[mt][0], kf[nb][0], z, 0, 0, 0);
      sv[mt][nb] = __builtin_amdgcn_mfma_f32_16x16x32_bf16(qf[mt][1], kf[nb][1], z, 0, 0, 0);
    }
  float mx[2][4];
  for (int mt = 0; mt < 2; ++mt)
    for (int i = 0; i < 4; ++i) {
      int rowg = q0 + mt * 16 + lg * 4 + i;
      float m = -1e30f;
      for (int nb = 0; nb < 4; ++nb) {
        int colg = q0 + nb * 16 + lr;
        float t = sv[mt][nb][i];
        bool valid = (colg > rowg) && (colg <= rowg + 32) && (colg < S_LEN);
        if (!valid) t = -1e30f;
        sv[mt][nb][i] = t;
        m = fmaxf(m, t);
      }
      mx[mt][i] = m;
    }
  for (int off = 1; off < 16; off <<= 1)
    for (int mt = 0; mt < 2; ++mt)
      for (int i = 0; i < 4; ++i) mx[mt][i] = fmaxf(mx[mt][i], __shfl_xor(mx[mt][i], off));
  float rs[2][4] = {{0.f, 0.f, 0.f, 0.f}, {0.f, 0.f, 0.f, 0.f}};
  for (int mt = 0; mt < 2; ++mt)
    for (int nb = 0; nb < 4; ++nb)
      for (int i = 0; i < 4; ++i) {
        float p = exp2f(sv[mt][nb][i] - mx[mt][i]);
        rs[mt][i] += p;
        Pw[(mt * 16 + lg * 4 + i) * 72 + nb * 16 + lr] = f2bf_n(p);
      }
  for (int off = 1; off < 16; off <<= 1)
    for (int mt = 0; mt < 2; ++mt)
      for (int i = 0; i < 4; ++i) rs[mt][i] += __shfl_xor(rs[mt][i], off);
  bfrag vf[4][2];
  for (int nd = 0; nd < 4; ++nd)
    for (int kc = 0; kc < 2; ++kc) {
      int sbase = q0 + kc * 32 + lg * 8;
      sbase = min(sbase, S_LEN - 8);
      vf[nd][kc] = *reinterpret_cast<const bfrag*>(
          VT + hb + (size_t)(nd * 16 + lr) * S_LEN + sbase);
    }
  f32x4 oacc[2][4];
  for (int mt = 0; mt < 2; ++mt)
    for (int nd = 0; nd < 4; ++nd) oacc[mt][nd] = {0.f, 0.f, 0.f, 0.f};
  for (int mt = 0; mt < 2; ++mt) {
    bfrag pa0 = *reinterpret_cast<const bfrag*>(&Pw[(mt * 16 + lr) * 72 + lg * 8]);
    bfrag pa1 = *reinterpret_cast<const bfrag*>(&Pw[(mt * 16 + lr) * 72 + 32 + lg * 8]);
    for (int nd = 0; nd < 4; ++nd) {
      oacc[mt][nd] = __builtin_amdgcn_mfma_f32_16x16x32_bf16(pa0, vf[nd][0], oacc[mt][nd], 0, 0, 0);
      oacc[mt][nd] = __builtin_amdgcn_mfma_f32_16x16x32_bf16(pa1, vf[nd][1], oacc[mt][nd], 0, 0, 0);
    }
  }
  for (int mt = 0; mt < 2; ++mt)
    for (int nd = 0; nd < 4; ++nd)
      for (int i = 0; i < 4; ++i) {
        int rowg = q0 + mt * 16 + lg * 4 + i;
        float ov = oacc[mt][nd][i] / rs[mt][i];
        bwd[(size_t)(b * S_LEN + rowg) * DMODEL + h * HD + nd * 16 + lr] = f2bf(ov);
      }
}

// ---------------- row S-1 of bwd: uniform mean over all Vb keys ----------------
__global__ __launch_bounds__(256) void vmean_kernel(const short* __restrict__ VT,
                                                    short* __restrict__ bwd) {
  __shared__ float red[256];
  const int bh = blockIdx.x;  // b*NH + h
  const int d = threadIdx.x >> 2;
  const int seg = threadIdx.x & 3;
  const short* row = VT + (size_t)bh * S_LEN * HD + (size_t)d * S_LEN + seg * 512;
  float s = 0.f;
  for (int j = 0; j < 512; j += 8) {
    uint4 v = *reinterpret_cast<const uint4*>(row + j);
    s += bflo(v.x) + bfhi(v.x) + bflo(v.y) + bfhi(v.y) +
         bflo(v.z) + bfhi(v.z) + bflo(v.w) + bfhi(v.w);
  }
  red[threadIdx.x] = s;
  __syncthreads();
  if (seg == 0) {
    float t = red[d * 4] + red[d * 4 + 1] + red[d * 4 + 2] + red[d * 4 + 3];
    int b = bh >> 4, h = bh & 15;
    bwd[((size_t)(b * S_LEN + S_LEN - 1)) * DMODEL + h * HD + d] = f2bf(t * (1.f / S_LEN));
  }
}

// ---------------- gate LN + sigmoid + fuse ----------------
__global__ __launch_bounds__(256) void ln_gate_fuse_kernel(
    const float* __restrict__ glin, const float* __restrict__ gln_g,
    const float* __restrict__ gln_b, const short* __restrict__ fwd,
    const short* __restrict__ bwd, const float* __restrict__ bstr,
    short* __restrict__ fused) {
  __shared__ float red[8];
  const int row = blockIdx.x;
  const int tid = threadIdx.x;
  const int lane = tid & 63;
  const int w = tid >> 6;
  float4 x = *reinterpret_cast<const float4*>(glin + (size_t)row * DMODEL + tid * 4);
  float xa[4] = {x.x, x.y, x.z, x.w};
  float s = xa[0] + xa[1] + xa[2] + xa[3];
  float ss = xa[0] * xa[0] + xa[1] * xa[1] + xa[2] * xa[2] + xa[3] * xa[3];
  for (int off = 1; off < 64; off <<= 1) {
    s += __shfl_xor(s, off);
    ss += __shfl_xor(ss, off);
  }
  if (lane == 0) { red[w] = s; red[4 + w] = ss; }
  __syncthreads();
  s = red[0] + red[1] + red[2] + red[3];
  ss = red[4] + red[5] + red[6] + red[7];
  const float mean = s * (1.f / DMODEL);
  const float var = ss * (1.f / DMODEL) - mean * mean;
  const float rstd = rsqrtf(var + 1e-5f);
  const float strength = 0.3f / (1.f + __expf(-bstr[0]));
  for (int e = 0; e < 4; ++e) {
    int idx = tid * 4 + e;
    float g = (xa[e] - mean) * rstd * gln_g[idx] + gln_b[idx];
    float gate = 1.f / (1.f + __expf(-g));
    float f = bf2f(fwd[(size_t)row * DMODEL + idx]) +
              strength * gate * bf2f(bwd[(size_t)row * DMODEL + idx]);
    fused[(size_t)row * DMODEL + idx] = f2bf(f);
  }
}

// ---------------- final residual LN ----------------
__global__ __launch_bounds__(256) void final_ln_kernel(const float* __restrict__ x,
                                                       const float* __restrict__ outb,
                                                       const float* __restrict__ ln_g,
                                                       const float* __restrict__ ln_b,
                                                       float* __restrict__ y) {
  __shared__ float red[8];
  const int row = blockIdx.x;
  const int tid = threadIdx.x;
  const int lane = tid & 63;
  const int w = tid >> 6;
  float4 xv = *reinterpret_cast<const float4*>(x + (size_t)row * DMODEL + tid * 4);
  float4 ov = *reinterpret_cast<const float4*>(outb + (size_t)row * DMODEL + tid * 4);
  float t[4] = {xv.x + ov.x, xv.y + ov.y, xv.z + ov.z, xv.w + ov.w};
  float s = t[0] + t[1] + t[2] + t[3];
  float ss = t[0] * t[0] + t[1] * t[1] + t[2] * t[2] + t[3] * t[3];
  for (int off = 1; off < 64; off <<= 1) {
    s += __shfl_xor(s, off);
    ss += __shfl_xor(ss, off);
  }
  if (lane == 0) { red[w] = s; red[4 + w] = ss; }
  __syncthreads();
  s = red[0] + red[1] + red[2] + red[3];
  ss = red[4] + red[5] + red[6] + red[7];
  const float mean = s * (1.f / DMODEL);
  const float var = ss * (1.f / DMODEL) - mean * mean;
  const float rstd = rsqrtf(var + 1e-5f);
  for (int e = 0; e < 4; ++e) {
    int idx = tid * 4 + e;
    y[(size_t)row * DMODEL + idx] = (t[e] - mean) * rstd * ln_g[idx] + ln_b[idx];
  }
}

extern "C" void kernel_launch(void* const* d_in, const int* in_sizes, int n_in,
                              void* d_out, int out_size, void* d_ws, size_t ws_size,
                              hipStream_t stream) {
  const float* x = (const float*)d_in[0];
  const float* fq_w = (const float*)d_in[1];
  const float* fq_b = (const float*)d_in[2];
  const float* fk_w = (const float*)d_in[3];
  const float* fk_b = (const float*)d_in[4];
  const float* fv_w = (const float*)d_in[5];
  const float* fv_b = (const float*)d_in[6];
  const float* bq_w = (const float*)d_in[7];
  const float* bq_b = (const float*)d_in[8];
  const float* bk_w = (const float*)d_in[9];
  const float* bk_b = (const float*)d_in[10];
  const float* bv_w = (const float*)d_in[11];
  const float* bv_b = (const float*)d_in[12];
  const float* gate_w = (const float*)d_in[13];
  const float* gate_b = (const float*)d_in[14];
  const float* gln_g = (const float*)d_in[15];
  const float* gln_b = (const float*)d_in[16];
  const float* bstr = (const float*)d_in[17];
  const float* out_w = (const float*)d_in[18];
  const float* out_b = (const float*)d_in[19];
  const float* ln_g = (const float*)d_in[20];
  const float* ln_b = (const float*)d_in[21];

  char* ws = (char*)d_ws;
  const size_t MB = 1u << 20;
  short* xb = (short*)(ws + 0);
  short* wT0 = (short*)(ws + 8 * MB);
  short* wT1 = (short*)(ws + 10 * MB);
  short* wT2 = (short*)(ws + 12 * MB);
  short* wT3 = (short*)(ws + 14 * MB);
  short* wT4 = (short*)(ws + 16 * MB);
  short* wT5 = (short*)(ws + 18 * MB);
  short* gwT = (short*)(ws + 20 * MB);
  short* owT = (short*)(ws + 24 * MB);
  short* qkv = (short*)(ws + 26 * MB);
  short* fwd = (short*)(ws + 0);
  short* bwdb = (short*)(ws + 8 * MB);
  float* glin = (float*)(ws + 26 * MB);
  short* fused = (short*)(ws + 42 * MB);
  float* outb = (float*)(ws + 50 * MB);

  cvt_bf16_kernel<<<4096, 256, 0, stream>>>(x, xb, ELTS_PER);
  transpose_cvt_all<<<dim3(32, 64, 8), dim3(32, 8), 0, stream>>>(
      fq_w, fk_w, fv_w, bq_w, bk_w, bv_w, out_w, gate_w,
      wT0, wT1, wT2, wT3, wT4, wT5, owT, gwT);

  gemm_kernel<0><<<dim3(48, 32), 256, 0, stream>>>(
      xb, xb, 1024, 1024, 1024, wT0, wT1, wT2, wT3, wT4, wT5,
      fq_b, fk_b, fv_b, bq_b, bk_b, bv_b, nullptr, qkv);

  attn_fwd_kernel<<<dim3(32, 16, 2), 256, 0, stream>>>(
      qkv, qkv + (size_t)ELTS_PER, qkv + 2 * (size_t)ELTS_PER, fwd);
  attn_bwd_kernel<<<dim3(16, 16, 2), 256, 0, stream>>>(
      qkv + 3 * (size_t)ELTS_PER, qkv + 4 * (size_t)ELTS_PER, qkv + 5 * (size_t)ELTS_PER, bwdb);
  vmean_kernel<<<32, 256, 0, stream>>>(qkv + 5 * (size_t)ELTS_PER, bwdb);

  gemm_kernel<1><<<dim3(8, 32), 256, 0, stream>>>(
      fwd, bwdb, 1024, 1024, 2048, gwT, gwT, gwT, gwT, gwT, gwT,
      gate_b, gate_b, gate_b, gate_b, gate_b, gate_b, glin, nullptr);

  ln_gate_fuse_kernel<<<4096, 256, 0, stream>>>(glin, gln_g, gln_b, fwd, bwdb, bstr, fused);

  gemm_kernel<1><<<dim3(8, 32), 256, 0, stream>>>(
      fused, fused, 1024, 1024, 1024, owT, owT, owT, owT, owT, owT,
      out_b, out_b, out_b, out_b, out_b, out_b, outb, nullptr);

  final_ln_kernel<<<4096, 256, 0, stream>>>(x, outb, ln_g, ln_b, (float*)d_out);
}

// Round 5
// 292.877 us; speedup vs baseline: 1.7997x; 1.1651x over previous
//
#include <hip/hip_runtime.h>

#define S_LEN 2048
#define NH 16
#define HD 64
#define DMODEL 1024
#define NTOK 4096
#define ELTS_PER 4194304  // B*S*D = NTOK*DMODEL
#define QSCALE 0.18033688f  // 0.125 * log2(e), folded into Q/Qb projections

typedef __attribute__((ext_vector_type(8))) __bf16 bfrag;
typedef __attribute__((ext_vector_type(8))) short s8v;
typedef __attribute__((ext_vector_type(4))) float f32x4;

__device__ inline float bf2f(short s) {
  unsigned int u = ((unsigned int)(unsigned short)s) << 16;
  float f;
  __builtin_memcpy(&f, &u, 4);
  return f;
}
__device__ inline short f2bf(float f) {
  unsigned int u;
  __builtin_memcpy(&u, &f, 4);
  u = (u + 0x7fffu + ((u >> 16) & 1u)) >> 16;
  return (short)u;
}
__device__ inline short f2bf_n(float f) {  // native convert (compiler picks cvt_pk)
  __bf16 h = (__bf16)f;
  short s;
  __builtin_memcpy(&s, &h, 2);
  return s;
}
__device__ inline float bflo(unsigned int u) {
  unsigned int t = u << 16;
  float f; __builtin_memcpy(&f, &t, 4); return f;
}
__device__ inline float bfhi(unsigned int u) {
  unsigned int t = u & 0xffff0000u;
  float f; __builtin_memcpy(&f, &t, 4); return f;
}
// async global -> LDS, 16B per lane (dest = wave-uniform base + lane*16)
__device__ __forceinline__ void gll16(const short* g, short* l) {
  __builtin_amdgcn_global_load_lds(
      (const __attribute__((address_space(1))) void*)g,
      (__attribute__((address_space(3))) void*)l, 16, 0, 0);
}

// ---------------- convert x: f32 -> bf16 ----------------
__global__ __launch_bounds__(256) void cvt_bf16_kernel(const float* __restrict__ in,
                                                       short* __restrict__ out, int n) {
  int i = (blockIdx.x * 256 + threadIdx.x) * 4;
  if (i + 3 < n) {
    float4 v = *reinterpret_cast<const float4*>(in + i);
    short4 o;
    o.x = f2bf(v.x); o.y = f2bf(v.y); o.z = f2bf(v.z); o.w = f2bf(v.w);
    *reinterpret_cast<short4*>(out + i) = o;
  }
}

// ---------- transpose + convert ALL weights: f32 [K][N=1024] -> bf16 [N][K] ----------
__global__ void transpose_cvt_all(const float* __restrict__ s0, const float* __restrict__ s1,
                                  const float* __restrict__ s2, const float* __restrict__ s3,
                                  const float* __restrict__ s4, const float* __restrict__ s5,
                                  const float* __restrict__ s6, const float* __restrict__ s7,
                                  short* d0, short* d1, short* d2, short* d3,
                                  short* d4, short* d5, short* d6, short* d7) {
  const int z = blockIdx.z;
  const int K = (z == 7) ? 2048 : 1024;
  if (blockIdx.y * 32 >= K) return;
  const float* srcs[8] = {s0, s1, s2, s3, s4, s5, s6, s7};
  short* dsts[8] = {d0, d1, d2, d3, d4, d5, d6, d7};
  const float* in = srcs[z];
  short* out = dsts[z];
  __shared__ float tile[32][33];
  int nb = blockIdx.x * 32, kb = blockIdx.y * 32;
  int tx = threadIdx.x, ty = threadIdx.y;  // block (32,8)
  for (int j = 0; j < 32; j += 8)
    tile[ty + j][tx] = in[(size_t)(kb + ty + j) * 1024 + nb + tx];
  __syncthreads();
  for (int j = 0; j < 32; j += 8)
    out[(size_t)(nb + ty + j) * K + kb + tx] = f2bf(tile[tx][ty + j]);
}

// ---------------- GEMM: C[M,N] = A[M,K] @ B^T[N,K]^T + bias ----------------
// global_load_lds staging into linear LDS [128][32].
// MODE 0: N=6144, scatter bf16 into per-head QKV buffers. V (nsel==2) and
//         Vb (nsel==5) written TRANSPOSED [b,h,d,s]; Q (0) and Qb (3) scaled by QSCALE.
// MODE 1: N=1024, f32 output [M,1024] + bias
template <int MODE>
__global__ __launch_bounds__(256) void gemm_kernel(
    const short* __restrict__ A0, const short* __restrict__ A1, int lda, int ksplit, int K,
    const short* __restrict__ B0, const short* __restrict__ B1, const short* __restrict__ B2,
    const short* __restrict__ B3, const short* __restrict__ B4, const short* __restrict__ B5,
    const float* __restrict__ bias0, const float* __restrict__ bias1,
    const float* __restrict__ bias2, const float* __restrict__ bias3,
    const float* __restrict__ bias4, const float* __restrict__ bias5,
    float* __restrict__ outF, short* __restrict__ outQ) {
  __shared__ short As[128 * 32];
  __shared__ short Bs[128 * 32];
  const int tid = threadIdx.x;
  const int n0 = blockIdx.x * 128;
  const int m0 = blockIdx.y * 128;
  const short* Bp[6] = {B0, B1, B2, B3, B4, B5};
  const float* biasP[6] = {bias0, bias1, bias2, bias3, bias4, bias5};
  const int nsel = n0 >> 10;
  const short* Bt = Bp[nsel] + (size_t)(n0 & 1023) * K;
  const float* bsel = biasP[nsel];

  const int lane = tid & 63;
  const int w = tid >> 6;
  const int wm = (w >> 1) * 64;
  const int wn = (w & 1) * 64;
  const int lr = lane & 15;
  const int lg = lane >> 4;
  const int gr = lane >> 2;        // staging: row within 16-row group
  const int gs = (lane & 3) * 8;   // staging: elem offset (16 B)

  f32x4 acc[4][4];
  for (int a = 0; a < 4; ++a)
    for (int b = 0; b < 4; ++b) acc[a][b] = {0.f, 0.f, 0.f, 0.f};

  for (int k0 = 0; k0 < K; k0 += 32) {
    const short* Abase;
    int kc;
    if (k0 < ksplit) { Abase = A0; kc = k0; } else { Abase = A1; kc = k0 - ksplit; }
    __syncthreads();
    const short* Ag = Abase + (size_t)(m0 + w * 32 + gr) * lda + kc + gs;
    const short* Bg = Bt + (size_t)(w * 32 + gr) * K + k0 + gs;
    gll16(Ag, &As[(w * 32) * 32]);
    gll16(Ag + (size_t)16 * lda, &As[(w * 32 + 16) * 32]);
    gll16(Bg, &Bs[(w * 32) * 32]);
    gll16(Bg + (size_t)16 * K, &Bs[(w * 32 + 16) * 32]);
    __syncthreads();
    bfrag af[4], bfr[4];
    for (int t = 0; t < 4; ++t) {
      af[t] = *reinterpret_cast<const bfrag*>(&As[(wm + t * 16 + lr) * 32 + lg * 8]);
      bfr[t] = *reinterpret_cast<const bfrag*>(&Bs[(wn + t * 16 + lr) * 32 + lg * 8]);
    }
    for (int mt = 0; mt < 4; ++mt)
      for (int nt = 0; nt < 4; ++nt)
        acc[mt][nt] = __builtin_amdgcn_mfma_f32_16x16x32_bf16(af[mt], bfr[nt], acc[mt][nt], 0, 0, 0);
  }

  const float cmul = (MODE == 0 && (nsel == 0 || nsel == 3)) ? QSCALE : 1.0f;
  for (int mt = 0; mt < 4; ++mt)
    for (int nt = 0; nt < 4; ++nt) {
      if constexpr (MODE == 0) {
        int rowb = m0 + wm + mt * 16 + lg * 4;
        int col = n0 + wn + nt * 16 + lr;
        int nh = col & 1023;
        int hh = nh >> 6, d = nh & 63;
        int bb = rowb >> 11, s0 = rowb & 2047;
        float bv = bsel[nh];
        if (nsel == 2 || nsel == 5) {
          short4 o;
          o.x = f2bf(acc[mt][nt][0] + bv);
          o.y = f2bf(acc[mt][nt][1] + bv);
          o.z = f2bf(acc[mt][nt][2] + bv);
          o.w = f2bf(acc[mt][nt][3] + bv);
          *reinterpret_cast<short4*>(
              outQ + (size_t)nsel * ELTS_PER +
              ((size_t)(bb * NH + hh) * HD + d) * S_LEN + s0) = o;
        } else {
          for (int i = 0; i < 4; ++i) {
            float v = (acc[mt][nt][i] + bv) * cmul;
            outQ[(size_t)nsel * ELTS_PER +
                 (((size_t)(bb * NH + hh) * S_LEN + (s0 + i)) * HD) + d] = f2bf(v);
          }
        }
      } else {
        for (int i = 0; i < 4; ++i) {
          int row = m0 + wm + mt * 16 + lg * 4 + i;
          int col = n0 + wn + nt * 16 + lr;
          outF[(size_t)row * DMODEL + col] = acc[mt][nt][i] + bias0[col];
        }
      }
    }
}

// ---------------- causal flash attention fwd (v4) ----------------
// 32 q-rows per wave; register-pipelined K (in-place reload after QK^T) and
// early-issued V loads; exp2 softmax (scores pre-scaled), ones-MFMA denominator.
// Flat 512-block grid, XCD-aware: xcd = f&7 owns 4 bh (K/V fits its L2).
// Mirrored chunk pairs (c, 63-c) keep per-block work constant.
__global__ __launch_bounds__(256) void attn_fwd_kernel(const short* __restrict__ Q,
                                                       const short* __restrict__ Kk,
                                                       const short* __restrict__ VT,
                                                       short* __restrict__ fwd) {
  __shared__ short Ps[4][32 * 72];
  const int tid = threadIdx.x;
  const int lane = tid & 63;
  const int w = tid >> 6;
  const int lr = lane & 15;
  const int lg = lane >> 4;
  const int f = blockIdx.x;              // 0..511
  const int xcd = f & 7;
  const int slot = f >> 3;               // 0..63
  const int bh = xcd * 4 + (slot >> 4);  // 0..31
  const int p = slot & 15;
  const int b = bh >> 4;
  const int h = bh & 15;
  const size_t hb = (size_t)(b * NH + h) * S_LEN * HD;
  short* Pw = Ps[w];

  s8v onesi = {0x3F80, 0x3F80, 0x3F80, 0x3F80, 0x3F80, 0x3F80, 0x3F80, 0x3F80};
  bfrag onesv;
  __builtin_memcpy(&onesv, &onesi, 16);

  const int c = (w < 2) ? (2 * p + w) : (63 - 2 * p - (w - 2));
  const int q0 = c * 32;
  const int ktm = c >> 1;

  bfrag qf[2][2];
  for (int mt = 0; mt < 2; ++mt)
    for (int kc = 0; kc < 2; ++kc)
      qf[mt][kc] = *reinterpret_cast<const bfrag*>(
          Q + hb + (size_t)(q0 + mt * 16 + lr) * HD + kc * 32 + lg * 8);

  f32x4 oacc[2][4];
  for (int mt = 0; mt < 2; ++mt)
    for (int nd = 0; nd < 4; ++nd) oacc[mt][nd] = {0.f, 0.f, 0.f, 0.f};
  f32x4 osum[2];
  osum[0] = {0.f, 0.f, 0.f, 0.f};
  osum[1] = {0.f, 0.f, 0.f, 0.f};

  bfrag ka[4][2];
  for (int nb = 0; nb < 4; ++nb)
    for (int kc = 0; kc < 2; ++kc)
      ka[nb][kc] = *reinterpret_cast<const bfrag*>(
          Kk + hb + (size_t)(nb * 16 + lr) * HD + kc * 32 + lg * 8);

  for (int kt = 0; kt <= ktm; ++kt) {
    // early V issue for this tile (independent of QK chain)
    bfrag vf[4][2];
    for (int nd = 0; nd < 4; ++nd)
      for (int kc = 0; kc < 2; ++kc)
        vf[nd][kc] = *reinterpret_cast<const bfrag*>(
            VT + hb + (size_t)(nd * 16 + lr) * S_LEN + kt * 64 + kc * 32 + lg * 8);
    // QK^T
    f32x4 sv[2][4];
    for (int mt = 0; mt < 2; ++mt)
      for (int nb = 0; nb < 4; ++nb) {
        f32x4 z = {0.f, 0.f, 0.f, 0.f};
        z = __builtin_amdgcn_mfma_f32_16x16x32_bf16(qf[mt][0], ka[nb][0], z, 0, 0, 0);
        sv[mt][nb] = __builtin_amdgcn_mfma_f32_16x16x32_bf16(qf[mt][1], ka[nb][1], z, 0, 0, 0);
      }
    // in-place prefetch of next K tile (WAR on ka orders it after the MFMAs;
    // latency hides under exp2 + LDS + PV below)
    if (kt < ktm) {
      for (int nb = 0; nb < 4; ++nb)
        for (int kc = 0; kc < 2; ++kc)
          ka[nb][kc] = *reinterpret_cast<const bfrag*>(
              Kk + hb + (size_t)((kt + 1) * 64 + nb * 16 + lr) * HD + kc * 32 + lg * 8);
    }
    // causal mask on diagonal tile only
    if (kt == ktm) {
      for (int mt = 0; mt < 2; ++mt)
        for (int nb = 0; nb < 4; ++nb)
          for (int i = 0; i < 4; ++i) {
            int colg = kt * 64 + nb * 16 + lr;
            int rowg = q0 + mt * 16 + lg * 4 + i;
            if (colg > rowg) sv[mt][nb][i] = -1e30f;
          }
    }
    // p = exp2(s) -> bf16 P tile (per-wave LDS, stride 72)
    for (int mt = 0; mt < 2; ++mt)
      for (int nb = 0; nb < 4; ++nb)
        for (int i = 0; i < 4; ++i)
          Pw[(mt * 16 + lg * 4 + i) * 72 + nb * 16 + lr] = f2bf_n(exp2f(sv[mt][nb][i]));
    // PV + denominator
    for (int mt = 0; mt < 2; ++mt) {
      bfrag pa0 = *reinterpret_cast<const bfrag*>(&Pw[(mt * 16 + lr) * 72 + lg * 8]);
      bfrag pa1 = *reinterpret_cast<const bfrag*>(&Pw[(mt * 16 + lr) * 72 + 32 + lg * 8]);
      for (int nd = 0; nd < 4; ++nd) {
        oacc[mt][nd] = __builtin_amdgcn_mfma_f32_16x16x32_bf16(pa0, vf[nd][0], oacc[mt][nd], 0, 0, 0);
        oacc[mt][nd] = __builtin_amdgcn_mfma_f32_16x16x32_bf16(pa1, vf[nd][1], oacc[mt][nd], 0, 0, 0);
      }
      osum[mt] = __builtin_amdgcn_mfma_f32_16x16x32_bf16(pa0, onesv, osum[mt], 0, 0, 0);
      osum[mt] = __builtin_amdgcn_mfma_f32_16x16x32_bf16(pa1, onesv, osum[mt], 0, 0, 0);
    }
  }

  for (int mt = 0; mt < 2; ++mt)
    for (int i = 0; i < 4; ++i) {
      int rowg = q0 + mt * 16 + lg * 4 + i;
      float inv = 1.0f / osum[mt][i];
      for (int nd = 0; nd < 4; ++nd)
        fwd[(size_t)(b * S_LEN + rowg) * DMODEL + h * HD + nd * 16 + lr] =
            f2bf(oacc[mt][nd][i] * inv);
    }
}

// ---------------- windowed backward attention (MFMA single-tile) ----------------
// Qb pre-scaled by QSCALE; exp2 softmax with per-row max (single tile, cheap).
__global__ __launch_bounds__(256) void attn_bwd_kernel(const short* __restrict__ Qb,
                                                       const short* __restrict__ Kb,
                                                       const short* __restrict__ VT,
                                                       short* __restrict__ bwd) {
  __shared__ short Ps[4][32 * 72];
  const int tid = threadIdx.x;
  const int lane = tid & 63;
  const int w = tid >> 6;
  const int lr = lane & 15;
  const int lg = lane >> 4;
  const int h = blockIdx.y;
  const int b = blockIdx.z;
  const size_t hb = (size_t)(b * NH + h) * S_LEN * HD;
  const int q0 = blockIdx.x * 128 + w * 32;
  short* Pw = Ps[w];

  bfrag qf[2][2];
  for (int mt = 0; mt < 2; ++mt)
    for (int kc = 0; kc < 2; ++kc)
      qf[mt][kc] = *reinterpret_cast<const bfrag*>(
          Qb + hb + (size_t)(q0 + mt * 16 + lr) * HD + kc * 32 + lg * 8);
  bfrag kf[4][2];
  for (int nb = 0; nb < 4; ++nb) {
    int kr = q0 + nb * 16 + lr;
    kr = min(kr, S_LEN - 1);
    for (int kc = 0; kc < 2; ++kc)
      kf[nb][kc] = *reinterpret_cast<const bfrag*>(
          Kb + hb + (size_t)kr * HD + kc * 32 + lg * 8);
  }
  f32x4 sv[2][4];
  for (int mt = 0; mt < 2; ++mt)
    for (int nb = 0; nb < 4; ++nb) {
      f32x4 z = {0.f, 0.f, 0.f, 0.f};
      z = __builtin_amdgcn_mfma_f32_16x16x32_bf16(qf[mt][0], kf[nb][0], z, 0, 0, 0);
      sv[mt][nb] = __builtin_amdgcn_mfma_f32_16x16x32_bf16(qf[mt][1], kf[nb][1], z, 0, 0, 0);
    }
  float mx[2][4];
  for (int mt = 0; mt < 2; ++mt)
    for (int i = 0; i < 4; ++i) {
      int rowg = q0 + mt * 16 + lg * 4 + i;
      float m = -1e30f;
      for (int nb = 0; nb < 4; ++nb) {
        int colg = q0 + nb * 16 + lr;
        float t = sv[mt][nb][i];
        bool valid = (colg > rowg) && (colg <= rowg + 32) && (colg < S_LEN);
        if (!valid) t = -1e30f;
        sv[mt][nb][i] = t;
        m = fmaxf(m, t);
      }
      mx[mt][i] = m;
    }
  for (int off = 1; off < 16; off <<= 1)
    for (int mt = 0; mt < 2; ++mt)
      for (int i = 0; i < 4; ++i) mx[mt][i] = fmaxf(mx[mt][i], __shfl_xor(mx[mt][i], off));
  float rs[2][4] = {{0.f, 0.f, 0.f, 0.f}, {0.f, 0.f, 0.f, 0.f}};
  for (int mt = 0; mt < 2; ++mt)
    for (int nb = 0; nb < 4; ++nb)
      for (int i = 0; i < 4; ++i) {
        float p = exp2f(sv[mt][nb][i] - mx[mt][i]);
        rs[mt][i] += p;
        Pw[(mt * 16 + lg * 4 + i) * 72 + nb * 16 + lr] = f2bf_n(p);
      }
  for (int off = 1; off < 16; off <<= 1)
    for (int mt = 0; mt < 2; ++mt)
      for (int i = 0; i < 4; ++i) rs[mt][i] += __shfl_xor(rs[mt][i], off);
  bfrag vf[4][2];
  for (int nd = 0; nd < 4; ++nd)
    for (int kc = 0; kc < 2; ++kc) {
      int sbase = q0 + kc * 32 + lg * 8;
      sbase = min(sbase, S_LEN - 8);
      vf[nd][kc] = *reinterpret_cast<const bfrag*>(
          VT + hb + (size_t)(nd * 16 + lr) * S_LEN + sbase);
    }
  f32x4 oacc[2][4];
  for (int mt = 0; mt < 2; ++mt)
    for (int nd = 0; nd < 4; ++nd) oacc[mt][nd] = {0.f, 0.f, 0.f, 0.f};
  for (int mt = 0; mt < 2; ++mt) {
    bfrag pa0 = *reinterpret_cast<const bfrag*>(&Pw[(mt * 16 + lr) * 72 + lg * 8]);
    bfrag pa1 = *reinterpret_cast<const bfrag*>(&Pw[(mt * 16 + lr) * 72 + 32 + lg * 8]);
    for (int nd = 0; nd < 4; ++nd) {
      oacc[mt][nd] = __builtin_amdgcn_mfma_f32_16x16x32_bf16(pa0, vf[nd][0], oacc[mt][nd], 0, 0, 0);
      oacc[mt][nd] = __builtin_amdgcn_mfma_f32_16x16x32_bf16(pa1, vf[nd][1], oacc[mt][nd], 0, 0, 0);
    }
  }
  for (int mt = 0; mt < 2; ++mt)
    for (int nd = 0; nd < 4; ++nd)
      for (int i = 0; i < 4; ++i) {
        int rowg = q0 + mt * 16 + lg * 4 + i;
        float ov = oacc[mt][nd][i] / rs[mt][i];
        bwd[(size_t)(b * S_LEN + rowg) * DMODEL + h * HD + nd * 16 + lr] = f2bf(ov);
      }
}

// ---------------- row S-1 of bwd: uniform mean over all Vb keys ----------------
__global__ __launch_bounds__(256) void vmean_kernel(const short* __restrict__ VT,
                                                    short* __restrict__ bwd) {
  __shared__ float red[256];
  const int bh = blockIdx.x;  // b*NH + h
  const int d = threadIdx.x >> 2;
  const int seg = threadIdx.x & 3;
  const short* row = VT + (size_t)bh * S_LEN * HD + (size_t)d * S_LEN + seg * 512;
  float s = 0.f;
  for (int j = 0; j < 512; j += 8) {
    uint4 v = *reinterpret_cast<const uint4*>(row + j);
    s += bflo(v.x) + bfhi(v.x) + bflo(v.y) + bfhi(v.y) +
         bflo(v.z) + bfhi(v.z) + bflo(v.w) + bfhi(v.w);
  }
  red[threadIdx.x] = s;
  __syncthreads();
  if (seg == 0) {
    float t = red[d * 4] + red[d * 4 + 1] + red[d * 4 + 2] + red[d * 4 + 3];
    int b = bh >> 4, h = bh & 15;
    bwd[((size_t)(b * S_LEN + S_LEN - 1)) * DMODEL + h * HD + d] = f2bf(t * (1.f / S_LEN));
  }
}

// ---------------- gate LN + sigmoid + fuse ----------------
__global__ __launch_bounds__(256) void ln_gate_fuse_kernel(
    const float* __restrict__ glin, const float* __restrict__ gln_g,
    const float* __restrict__ gln_b, const short* __restrict__ fwd,
    const short* __restrict__ bwd, const float* __restrict__ bstr,
    short* __restrict__ fused) {
  __shared__ float red[8];
  const int row = blockIdx.x;
  const int tid = threadIdx.x;
  const int lane = tid & 63;
  const int w = tid >> 6;
  float4 x = *reinterpret_cast<const float4*>(glin + (size_t)row * DMODEL + tid * 4);
  float xa[4] = {x.x, x.y, x.z, x.w};
  float s = xa[0] + xa[1] + xa[2] + xa[3];
  float ss = xa[0] * xa[0] + xa[1] * xa[1] + xa[2] * xa[2] + xa[3] * xa[3];
  for (int off = 1; off < 64; off <<= 1) {
    s += __shfl_xor(s, off);
    ss += __shfl_xor(ss, off);
  }
  if (lane == 0) { red[w] = s; red[4 + w] = ss; }
  __syncthreads();
  s = red[0] + red[1] + red[2] + red[3];
  ss = red[4] + red[5] + red[6] + red[7];
  const float mean = s * (1.f / DMODEL);
  const float var = ss * (1.f / DMODEL) - mean * mean;
  const float rstd = rsqrtf(var + 1e-5f);
  const float strength = 0.3f / (1.f + __expf(-bstr[0]));
  for (int e = 0; e < 4; ++e) {
    int idx = tid * 4 + e;
    float g = (xa[e] - mean) * rstd * gln_g[idx] + gln_b[idx];
    float gate = 1.f / (1.f + __expf(-g));
    float f = bf2f(fwd[(size_t)row * DMODEL + idx]) +
              strength * gate * bf2f(bwd[(size_t)row * DMODEL + idx]);
    fused[(size_t)row * DMODEL + idx] = f2bf(f);
  }
}

// ---------------- final residual LN ----------------
__global__ __launch_bounds__(256) void final_ln_kernel(const float* __restrict__ x,
                                                       const float* __restrict__ outb,
                                                       const float* __restrict__ ln_g,
                                                       const float* __restrict__ ln_b,
                                                       float* __restrict__ y) {
  __shared__ float red[8];
  const int row = blockIdx.x;
  const int tid = threadIdx.x;
  const int lane = tid & 63;
  const int w = tid >> 6;
  float4 xv = *reinterpret_cast<const float4*>(x + (size_t)row * DMODEL + tid * 4);
  float4 ov = *reinterpret_cast<const float4*>(outb + (size_t)row * DMODEL + tid * 4);
  float t[4] = {xv.x + ov.x, xv.y + ov.y, xv.z + ov.z, xv.w + ov.w};
  float s = t[0] + t[1] + t[2] + t[3];
  float ss = t[0] * t[0] + t[1] * t[1] + t[2] * t[2] + t[3] * t[3];
  for (int off = 1; off < 64; off <<= 1) {
    s += __shfl_xor(s, off);
    ss += __shfl_xor(ss, off);
  }
  if (lane == 0) { red[w] = s; red[4 + w] = ss; }
  __syncthreads();
  s = red[0] + red[1] + red[2] + red[3];
  ss = red[4] + red[5] + red[6] + red[7];
  const float mean = s * (1.f / DMODEL);
  const float var = ss * (1.f / DMODEL) - mean * mean;
  const float rstd = rsqrtf(var + 1e-5f);
  for (int e = 0; e < 4; ++e) {
    int idx = tid * 4 + e;
    y[(size_t)row * DMODEL + idx] = (t[e] - mean) * rstd * ln_g[idx] + ln_b[idx];
  }
}

extern "C" void kernel_launch(void* const* d_in, const int* in_sizes, int n_in,
                              void* d_out, int out_size, void* d_ws, size_t ws_size,
                              hipStream_t stream) {
  const float* x = (const float*)d_in[0];
  const float* fq_w = (const float*)d_in[1];
  const float* fq_b = (const float*)d_in[2];
  const float* fk_w = (const float*)d_in[3];
  const float* fk_b = (const float*)d_in[4];
  const float* fv_w = (const float*)d_in[5];
  const float* fv_b = (const float*)d_in[6];
  const float* bq_w = (const float*)d_in[7];
  const float* bq_b = (const float*)d_in[8];
  const float* bk_w = (const float*)d_in[9];
  const float* bk_b = (const float*)d_in[10];
  const float* bv_w = (const float*)d_in[11];
  const float* bv_b = (const float*)d_in[12];
  const float* gate_w = (const float*)d_in[13];
  const float* gate_b = (const float*)d_in[14];
  const float* gln_g = (const float*)d_in[15];
  const float* gln_b = (const float*)d_in[16];
  const float* bstr = (const float*)d_in[17];
  const float* out_w = (const float*)d_in[18];
  const float* out_b = (const float*)d_in[19];
  const float* ln_g = (const float*)d_in[20];
  const float* ln_b = (const float*)d_in[21];

  char* ws = (char*)d_ws;
  const size_t MB = 1u << 20;
  short* xb = (short*)(ws + 0);
  short* wT0 = (short*)(ws + 8 * MB);
  short* wT1 = (short*)(ws + 10 * MB);
  short* wT2 = (short*)(ws + 12 * MB);
  short* wT3 = (short*)(ws + 14 * MB);
  short* wT4 = (short*)(ws + 16 * MB);
  short* wT5 = (short*)(ws + 18 * MB);
  short* gwT = (short*)(ws + 20 * MB);
  short* owT = (short*)(ws + 24 * MB);
  short* qkv = (short*)(ws + 26 * MB);
  short* fwd = (short*)(ws + 0);
  short* bwdb = (short*)(ws + 8 * MB);
  float* glin = (float*)(ws + 26 * MB);
  short* fused = (short*)(ws + 42 * MB);
  float* outb = (float*)(ws + 50 * MB);

  cvt_bf16_kernel<<<4096, 256, 0, stream>>>(x, xb, ELTS_PER);
  transpose_cvt_all<<<dim3(32, 64, 8), dim3(32, 8), 0, stream>>>(
      fq_w, fk_w, fv_w, bq_w, bk_w, bv_w, out_w, gate_w,
      wT0, wT1, wT2, wT3, wT4, wT5, owT, gwT);

  gemm_kernel<0><<<dim3(48, 32), 256, 0, stream>>>(
      xb, xb, 1024, 1024, 1024, wT0, wT1, wT2, wT3, wT4, wT5,
      fq_b, fk_b, fv_b, bq_b, bk_b, bv_b, nullptr, qkv);

  attn_fwd_kernel<<<512, 256, 0, stream>>>(
      qkv, qkv + (size_t)ELTS_PER, qkv + 2 * (size_t)ELTS_PER, fwd);
  attn_bwd_kernel<<<dim3(16, 16, 2), 256, 0, stream>>>(
      qkv + 3 * (size_t)ELTS_PER, qkv + 4 * (size_t)ELTS_PER, qkv + 5 * (size_t)ELTS_PER, bwdb);
  vmean_kernel<<<32, 256, 0, stream>>>(qkv + 5 * (size_t)ELTS_PER, bwdb);

  gemm_kernel<1><<<dim3(8, 32), 256, 0, stream>>>(
      fwd, bwdb, 1024, 1024, 2048, gwT, gwT, gwT, gwT, gwT, gwT,
      gate_b, gate_b, gate_b, gate_b, gate_b, gate_b, glin, nullptr);

  ln_gate_fuse_kernel<<<4096, 256, 0, stream>>>(glin, gln_g, gln_b, fwd, bwdb, bstr, fused);

  gemm_kernel<1><<<dim3(8, 32), 256, 0, stream>>>(
      fused, fused, 1024, 1024, 1024, owT, owT, owT, owT, owT, owT,
      out_b, out_b, out_b, out_b, out_b, out_b, outb, nullptr);

  final_ln_kernel<<<4096, 256, 0, stream>>>(x, outb, ln_g, ln_b, (float*)d_out);
}

// Round 6
// 276.729 us; speedup vs baseline: 1.9047x; 1.0584x over previous
//
#include <hip/hip_runtime.h>

#define S_LEN 2048
#define NH 16
#define HD 64
#define DMODEL 1024
#define NTOK 4096
#define ELTS_PER 4194304  // B*S*D = NTOK*DMODEL
#define QSCALE 0.18033688f  // 0.125 * log2(e), folded into Q/Qb projections

typedef __attribute__((ext_vector_type(8))) __bf16 bfrag;
typedef __attribute__((ext_vector_type(8))) short s8v;
typedef __attribute__((ext_vector_type(4))) float f32x4;

__device__ inline float bf2f(short s) {
  unsigned int u = ((unsigned int)(unsigned short)s) << 16;
  float f;
  __builtin_memcpy(&f, &u, 4);
  return f;
}
__device__ inline short f2bf(float f) {
  unsigned int u;
  __builtin_memcpy(&u, &f, 4);
  u = (u + 0x7fffu + ((u >> 16) & 1u)) >> 16;
  return (short)u;
}
__device__ inline short f2bf_n(float f) {  // native convert (packed cvt)
  __bf16 h = (__bf16)f;
  short s;
  __builtin_memcpy(&s, &h, 2);
  return s;
}
__device__ inline float bflo(unsigned int u) {
  unsigned int t = u << 16;
  float f; __builtin_memcpy(&f, &t, 4); return f;
}
__device__ inline float bfhi(unsigned int u) {
  unsigned int t = u & 0xffff0000u;
  float f; __builtin_memcpy(&f, &t, 4); return f;
}
// async global -> LDS, 16B per lane (dest = wave-uniform base + lane*16)
__device__ __forceinline__ void gll16(const short* g, short* l) {
  __builtin_amdgcn_global_load_lds(
      (const __attribute__((address_space(1))) void*)g,
      (__attribute__((address_space(3))) void*)l, 16, 0, 0);
}

// ---------------- convert x: f32 -> bf16 ----------------
__global__ __launch_bounds__(256) void cvt_bf16_kernel(const float* __restrict__ in,
                                                       short* __restrict__ out, int n) {
  int i = (blockIdx.x * 256 + threadIdx.x) * 4;
  if (i + 3 < n) {
    float4 v = *reinterpret_cast<const float4*>(in + i);
    short4 o;
    o.x = f2bf(v.x); o.y = f2bf(v.y); o.z = f2bf(v.z); o.w = f2bf(v.w);
    *reinterpret_cast<short4*>(out + i) = o;
  }
}

// ---------- transpose + convert ALL weights: f32 [K][N=1024] -> bf16 [N][K] ----------
__global__ void transpose_cvt_all(const float* __restrict__ s0, const float* __restrict__ s1,
                                  const float* __restrict__ s2, const float* __restrict__ s3,
                                  const float* __restrict__ s4, const float* __restrict__ s5,
                                  const float* __restrict__ s6, const float* __restrict__ s7,
                                  short* d0, short* d1, short* d2, short* d3,
                                  short* d4, short* d5, short* d6, short* d7) {
  const int z = blockIdx.z;
  const int K = (z == 7) ? 2048 : 1024;
  if (blockIdx.y * 32 >= K) return;
  const float* srcs[8] = {s0, s1, s2, s3, s4, s5, s6, s7};
  short* dsts[8] = {d0, d1, d2, d3, d4, d5, d6, d7};
  const float* in = srcs[z];
  short* out = dsts[z];
  __shared__ float tile[32][33];
  int nb = blockIdx.x * 32, kb = blockIdx.y * 32;
  int tx = threadIdx.x, ty = threadIdx.y;  // block (32,8)
  for (int j = 0; j < 32; j += 8)
    tile[ty + j][tx] = in[(size_t)(kb + ty + j) * 1024 + nb + tx];
  __syncthreads();
  for (int j = 0; j < 32; j += 8)
    out[(size_t)(nb + ty + j) * K + kb + tx] = f2bf(tile[tx][ty + j]);
}

// ---------------- QKV GEMM: C[4096,6144] = x @ 6 weights, scatter epilogue -----------
// global_load_lds staging into LDS [128][32] with XOR slot-swizzle:
// LDS[row][slot] holds global[row][slot ^ ((row&15)>>1 & 3)]; reads XOR the same.
__global__ __launch_bounds__(256) void gemm_qkv_kernel(
    const short* __restrict__ A, int lda, int K,
    const short* __restrict__ B0, const short* __restrict__ B1, const short* __restrict__ B2,
    const short* __restrict__ B3, const short* __restrict__ B4, const short* __restrict__ B5,
    const float* __restrict__ bias0, const float* __restrict__ bias1,
    const float* __restrict__ bias2, const float* __restrict__ bias3,
    const float* __restrict__ bias4, const float* __restrict__ bias5,
    short* __restrict__ outQ) {
  __shared__ short As[128 * 32];
  __shared__ short Bs[128 * 32];
  const int tid = threadIdx.x;
  const int n0 = blockIdx.x * 128;
  const int m0 = blockIdx.y * 128;
  const short* Bp[6] = {B0, B1, B2, B3, B4, B5};
  const float* biasP[6] = {bias0, bias1, bias2, bias3, bias4, bias5};
  const int nsel = n0 >> 10;
  const short* Bt = Bp[nsel] + (size_t)(n0 & 1023) * K;
  const float* bsel = biasP[nsel];

  const int lane = tid & 63;
  const int w = tid >> 6;
  const int wm = (w >> 1) * 64;
  const int wn = (w & 1) * 64;
  const int lr = lane & 15;
  const int lg = lane >> 4;
  const int gr = lane >> 2;                                // staging row in 16-group
  const int gs = (((lane & 3) ^ ((gr >> 1) & 3)) * 8);     // pre-swizzled source col
  const int rsw = (lr >> 1) & 3;                           // read-side swizzle

  f32x4 acc[4][4];
  for (int a = 0; a < 4; ++a)
    for (int b = 0; b < 4; ++b) acc[a][b] = {0.f, 0.f, 0.f, 0.f};

  for (int k0 = 0; k0 < K; k0 += 32) {
    __syncthreads();
    const short* Ag = A + (size_t)(m0 + w * 32 + gr) * lda + k0 + gs;
    const short* Bg = Bt + (size_t)(w * 32 + gr) * K + k0 + gs;
    gll16(Ag, &As[(w * 32) * 32]);
    gll16(Ag + (size_t)16 * lda, &As[(w * 32 + 16) * 32]);
    gll16(Bg, &Bs[(w * 32) * 32]);
    gll16(Bg + (size_t)16 * K, &Bs[(w * 32 + 16) * 32]);
    __syncthreads();
    bfrag af[4], bfr[4];
    for (int t = 0; t < 4; ++t) {
      af[t] = *reinterpret_cast<const bfrag*>(&As[(wm + t * 16 + lr) * 32 + ((lg ^ rsw) * 8)]);
      bfr[t] = *reinterpret_cast<const bfrag*>(&Bs[(wn + t * 16 + lr) * 32 + ((lg ^ rsw) * 8)]);
    }
    for (int mt = 0; mt < 4; ++mt)
      for (int nt = 0; nt < 4; ++nt)
        acc[mt][nt] = __builtin_amdgcn_mfma_f32_16x16x32_bf16(af[mt], bfr[nt], acc[mt][nt], 0, 0, 0);
  }

  const float cmul = (nsel == 0 || nsel == 3) ? QSCALE : 1.0f;
  for (int mt = 0; mt < 4; ++mt)
    for (int nt = 0; nt < 4; ++nt) {
      int rowb = m0 + wm + mt * 16 + lg * 4;
      int col = n0 + wn + nt * 16 + lr;
      int nh = col & 1023;
      int hh = nh >> 6, d = nh & 63;
      int bb = rowb >> 11, s0 = rowb & 2047;
      float bv = bsel[nh];
      if (nsel == 2 || nsel == 5) {
        short4 o;
        o.x = f2bf_n(acc[mt][nt][0] + bv);
        o.y = f2bf_n(acc[mt][nt][1] + bv);
        o.z = f2bf_n(acc[mt][nt][2] + bv);
        o.w = f2bf_n(acc[mt][nt][3] + bv);
        *reinterpret_cast<short4*>(
            outQ + (size_t)nsel * ELTS_PER +
            ((size_t)(bb * NH + hh) * HD + d) * S_LEN + s0) = o;
      } else {
        for (int i = 0; i < 4; ++i) {
          float v = (acc[mt][nt][i] + bv) * cmul;
          outQ[(size_t)nsel * ELTS_PER +
               (((size_t)(bb * NH + hh) * S_LEN + (s0 + i)) * HD) + d] = f2bf_n(v);
        }
      }
    }
}

// ---------------- K-split GEMM, f32 partial outputs ----------------
// blockIdx.z = k-chunk: z=0 -> A0, B cols [0,K), out0, +bias; z=1 -> A1,
// B cols [K,2K), out1, no bias. Consumer sums out0+out1.
__global__ __launch_bounds__(256) void gemm_ksplit_kernel(
    const short* __restrict__ A0, const short* __restrict__ A1, int lda,
    const short* __restrict__ B, int ldb, int K,
    const float* __restrict__ bias, float* __restrict__ out0, float* __restrict__ out1) {
  __shared__ short As[128 * 32];
  __shared__ short Bs[128 * 32];
  const int tid = threadIdx.x;
  const int n0 = blockIdx.x * 128;
  const int m0 = blockIdx.y * 128;
  const int z = blockIdx.z;
  const short* A = z ? A1 : A0;
  const short* Bt = B + (size_t)n0 * ldb + z * K;
  float* outp = z ? out1 : out0;

  const int lane = tid & 63;
  const int w = tid >> 6;
  const int wm = (w >> 1) * 64;
  const int wn = (w & 1) * 64;
  const int lr = lane & 15;
  const int lg = lane >> 4;
  const int gr = lane >> 2;
  const int gs = (((lane & 3) ^ ((gr >> 1) & 3)) * 8);
  const int rsw = (lr >> 1) & 3;

  f32x4 acc[4][4];
  for (int a = 0; a < 4; ++a)
    for (int b = 0; b < 4; ++b) acc[a][b] = {0.f, 0.f, 0.f, 0.f};

  for (int k0 = 0; k0 < K; k0 += 32) {
    __syncthreads();
    const short* Ag = A + (size_t)(m0 + w * 32 + gr) * lda + k0 + gs;
    const short* Bg = Bt + (size_t)(w * 32 + gr) * ldb + k0 + gs;
    gll16(Ag, &As[(w * 32) * 32]);
    gll16(Ag + (size_t)16 * lda, &As[(w * 32 + 16) * 32]);
    gll16(Bg, &Bs[(w * 32) * 32]);
    gll16(Bg + (size_t)16 * ldb, &Bs[(w * 32 + 16) * 32]);
    __syncthreads();
    bfrag af[4], bfr[4];
    for (int t = 0; t < 4; ++t) {
      af[t] = *reinterpret_cast<const bfrag*>(&As[(wm + t * 16 + lr) * 32 + ((lg ^ rsw) * 8)]);
      bfr[t] = *reinterpret_cast<const bfrag*>(&Bs[(wn + t * 16 + lr) * 32 + ((lg ^ rsw) * 8)]);
    }
    for (int mt = 0; mt < 4; ++mt)
      for (int nt = 0; nt < 4; ++nt)
        acc[mt][nt] = __builtin_amdgcn_mfma_f32_16x16x32_bf16(af[mt], bfr[nt], acc[mt][nt], 0, 0, 0);
  }

  for (int mt = 0; mt < 4; ++mt)
    for (int nt = 0; nt < 4; ++nt)
      for (int i = 0; i < 4; ++i) {
        int row = m0 + wm + mt * 16 + lg * 4 + i;
        int col = n0 + wn + nt * 16 + lr;
        float v = acc[mt][nt][i] + (z == 0 ? bias[col] : 0.f);
        outp[(size_t)row * DMODEL + col] = v;
      }
}

// ---------------- causal flash attention fwd (v4) ----------------
__global__ __launch_bounds__(256) void attn_fwd_kernel(const short* __restrict__ Q,
                                                       const short* __restrict__ Kk,
                                                       const short* __restrict__ VT,
                                                       short* __restrict__ fwd) {
  __shared__ short Ps[4][32 * 72];
  const int tid = threadIdx.x;
  const int lane = tid & 63;
  const int w = tid >> 6;
  const int lr = lane & 15;
  const int lg = lane >> 4;
  const int f = blockIdx.x;              // 0..511
  const int xcd = f & 7;
  const int slot = f >> 3;               // 0..63
  const int bh = xcd * 4 + (slot >> 4);  // 0..31
  const int p = slot & 15;
  const int b = bh >> 4;
  const int h = bh & 15;
  const size_t hb = (size_t)(b * NH + h) * S_LEN * HD;
  short* Pw = Ps[w];

  s8v onesi = {0x3F80, 0x3F80, 0x3F80, 0x3F80, 0x3F80, 0x3F80, 0x3F80, 0x3F80};
  bfrag onesv;
  __builtin_memcpy(&onesv, &onesi, 16);

  const int c = (w < 2) ? (2 * p + w) : (63 - 2 * p - (w - 2));
  const int q0 = c * 32;
  const int ktm = c >> 1;

  bfrag qf[2][2];
  for (int mt = 0; mt < 2; ++mt)
    for (int kc = 0; kc < 2; ++kc)
      qf[mt][kc] = *reinterpret_cast<const bfrag*>(
          Q + hb + (size_t)(q0 + mt * 16 + lr) * HD + kc * 32 + lg * 8);

  f32x4 oacc[2][4];
  for (int mt = 0; mt < 2; ++mt)
    for (int nd = 0; nd < 4; ++nd) oacc[mt][nd] = {0.f, 0.f, 0.f, 0.f};
  f32x4 osum[2];
  osum[0] = {0.f, 0.f, 0.f, 0.f};
  osum[1] = {0.f, 0.f, 0.f, 0.f};

  bfrag ka[4][2];
  for (int nb = 0; nb < 4; ++nb)
    for (int kc = 0; kc < 2; ++kc)
      ka[nb][kc] = *reinterpret_cast<const bfrag*>(
          Kk + hb + (size_t)(nb * 16 + lr) * HD + kc * 32 + lg * 8);

  for (int kt = 0; kt <= ktm; ++kt) {
    bfrag vf[4][2];
    for (int nd = 0; nd < 4; ++nd)
      for (int kc = 0; kc < 2; ++kc)
        vf[nd][kc] = *reinterpret_cast<const bfrag*>(
            VT + hb + (size_t)(nd * 16 + lr) * S_LEN + kt * 64 + kc * 32 + lg * 8);
    f32x4 sv[2][4];
    for (int mt = 0; mt < 2; ++mt)
      for (int nb = 0; nb < 4; ++nb) {
        f32x4 z = {0.f, 0.f, 0.f, 0.f};
        z = __builtin_amdgcn_mfma_f32_16x16x32_bf16(qf[mt][0], ka[nb][0], z, 0, 0, 0);
        sv[mt][nb] = __builtin_amdgcn_mfma_f32_16x16x32_bf16(qf[mt][1], ka[nb][1], z, 0, 0, 0);
      }
    if (kt < ktm) {
      for (int nb = 0; nb < 4; ++nb)
        for (int kc = 0; kc < 2; ++kc)
          ka[nb][kc] = *reinterpret_cast<const bfrag*>(
              Kk + hb + (size_t)((kt + 1) * 64 + nb * 16 + lr) * HD + kc * 32 + lg * 8);
    }
    if (kt == ktm) {
      for (int mt = 0; mt < 2; ++mt)
        for (int nb = 0; nb < 4; ++nb)
          for (int i = 0; i < 4; ++i) {
            int colg = kt * 64 + nb * 16 + lr;
            int rowg = q0 + mt * 16 + lg * 4 + i;
            if (colg > rowg) sv[mt][nb][i] = -1e30f;
          }
    }
    for (int mt = 0; mt < 2; ++mt)
      for (int nb = 0; nb < 4; ++nb)
        for (int i = 0; i < 4; ++i)
          Pw[(mt * 16 + lg * 4 + i) * 72 + nb * 16 + lr] = f2bf_n(exp2f(sv[mt][nb][i]));
    for (int mt = 0; mt < 2; ++mt) {
      bfrag pa0 = *reinterpret_cast<const bfrag*>(&Pw[(mt * 16 + lr) * 72 + lg * 8]);
      bfrag pa1 = *reinterpret_cast<const bfrag*>(&Pw[(mt * 16 + lr) * 72 + 32 + lg * 8]);
      for (int nd = 0; nd < 4; ++nd) {
        oacc[mt][nd] = __builtin_amdgcn_mfma_f32_16x16x32_bf16(pa0, vf[nd][0], oacc[mt][nd], 0, 0, 0);
        oacc[mt][nd] = __builtin_amdgcn_mfma_f32_16x16x32_bf16(pa1, vf[nd][1], oacc[mt][nd], 0, 0, 0);
      }
      osum[mt] = __builtin_amdgcn_mfma_f32_16x16x32_bf16(pa0, onesv, osum[mt], 0, 0, 0);
      osum[mt] = __builtin_amdgcn_mfma_f32_16x16x32_bf16(pa1, onesv, osum[mt], 0, 0, 0);
    }
  }

  for (int mt = 0; mt < 2; ++mt)
    for (int i = 0; i < 4; ++i) {
      int rowg = q0 + mt * 16 + lg * 4 + i;
      float inv = 1.0f / osum[mt][i];
      for (int nd = 0; nd < 4; ++nd)
        fwd[(size_t)(b * S_LEN + rowg) * DMODEL + h * HD + nd * 16 + lr] =
            f2bf(oacc[mt][nd][i] * inv);
    }
}

// ---------------- windowed backward attention (MFMA single-tile) ----------------
__global__ __launch_bounds__(256) void attn_bwd_kernel(const short* __restrict__ Qb,
                                                       const short* __restrict__ Kb,
                                                       const short* __restrict__ VT,
                                                       short* __restrict__ bwd) {
  __shared__ short Ps[4][32 * 72];
  const int tid = threadIdx.x;
  const int lane = tid & 63;
  const int w = tid >> 6;
  const int lr = lane & 15;
  const int lg = lane >> 4;
  const int h = blockIdx.y;
  const int b = blockIdx.z;
  const size_t hb = (size_t)(b * NH + h) * S_LEN * HD;
  const int q0 = blockIdx.x * 128 + w * 32;
  short* Pw = Ps[w];

  bfrag qf[2][2];
  for (int mt = 0; mt < 2; ++mt)
    for (int kc = 0; kc < 2; ++kc)
      qf[mt][kc] = *reinterpret_cast<const bfrag*>(
          Qb + hb + (size_t)(q0 + mt * 16 + lr) * HD + kc * 32 + lg * 8);
  bfrag kf[4][2];
  for (int nb = 0; nb < 4; ++nb) {
    int kr = q0 + nb * 16 + lr;
    kr = min(kr, S_LEN - 1);
    for (int kc = 0; kc < 2; ++kc)
      kf[nb][kc] = *reinterpret_cast<const bfrag*>(
          Kb + hb + (size_t)kr * HD + kc * 32 + lg * 8);
  }
  f32x4 sv[2][4];
  for (int mt = 0; mt < 2; ++mt)
    for (int nb = 0; nb < 4; ++nb) {
      f32x4 z = {0.f, 0.f, 0.f, 0.f};
      z = __builtin_amdgcn_mfma_f32_16x16x32_bf16(qf[mt][0], kf[nb][0], z, 0, 0, 0);
      sv[mt][nb] = __builtin_amdgcn_mfma_f32_16x16x32_bf16(qf[mt][1], kf[nb][1], z, 0, 0, 0);
    }
  float mx[2][4];
  for (int mt = 0; mt < 2; ++mt)
    for (int i = 0; i < 4; ++i) {
      int rowg = q0 + mt * 16 + lg * 4 + i;
      float m = -1e30f;
      for (int nb = 0; nb < 4; ++nb) {
        int colg = q0 + nb * 16 + lr;
        float t = sv[mt][nb][i];
        bool valid = (colg > rowg) && (colg <= rowg + 32) && (colg < S_LEN);
        if (!valid) t = -1e30f;
        sv[mt][nb][i] = t;
        m = fmaxf(m, t);
      }
      mx[mt][i] = m;
    }
  for (int off = 1; off < 16; off <<= 1)
    for (int mt = 0; mt < 2; ++mt)
      for (int i = 0; i < 4; ++i) mx[mt][i] = fmaxf(mx[mt][i], __shfl_xor(mx[mt][i], off));
  float rs[2][4] = {{0.f, 0.f, 0.f, 0.f}, {0.f, 0.f, 0.f, 0.f}};
  for (int mt = 0; mt < 2; ++mt)
    for (int nb = 0; nb < 4; ++nb)
      for (int i = 0; i < 4; ++i) {
        float p = exp2f(sv[mt][nb][i] - mx[mt][i]);
        rs[mt][i] += p;
        Pw[(mt * 16 + lg * 4 + i) * 72 + nb * 16 + lr] = f2bf_n(p);
      }
  for (int off = 1; off < 16; off <<= 1)
    for (int mt = 0; mt < 2; ++mt)
      for (int i = 0; i < 4; ++i) rs[mt][i] += __shfl_xor(rs[mt][i], off);
  bfrag vf[4][2];
  for (int nd = 0; nd < 4; ++nd)
    for (int kc = 0; kc < 2; ++kc) {
      int sbase = q0 + kc * 32 + lg * 8;
      sbase = min(sbase, S_LEN - 8);
      vf[nd][kc] = *reinterpret_cast<const bfrag*>(
          VT + hb + (size_t)(nd * 16 + lr) * S_LEN + sbase);
    }
  f32x4 oacc[2][4];
  for (int mt = 0; mt < 2; ++mt)
    for (int nd = 0; nd < 4; ++nd) oacc[mt][nd] = {0.f, 0.f, 0.f, 0.f};
  for (int mt = 0; mt < 2; ++mt) {
    bfrag pa0 = *reinterpret_cast<const bfrag*>(&Pw[(mt * 16 + lr) * 72 + lg * 8]);
    bfrag pa1 = *reinterpret_cast<const bfrag*>(&Pw[(mt * 16 + lr) * 72 + 32 + lg * 8]);
    for (int nd = 0; nd < 4; ++nd) {
      oacc[mt][nd] = __builtin_amdgcn_mfma_f32_16x16x32_bf16(pa0, vf[nd][0], oacc[mt][nd], 0, 0, 0);
      oacc[mt][nd] = __builtin_amdgcn_mfma_f32_16x16x32_bf16(pa1, vf[nd][1], oacc[mt][nd], 0, 0, 0);
    }
  }
  for (int mt = 0; mt < 2; ++mt)
    for (int nd = 0; nd < 4; ++nd)
      for (int i = 0; i < 4; ++i) {
        int rowg = q0 + mt * 16 + lg * 4 + i;
        float ov = oacc[mt][nd][i] / rs[mt][i];
        bwd[(size_t)(b * S_LEN + rowg) * DMODEL + h * HD + nd * 16 + lr] = f2bf(ov);
      }
}

// ---------------- row S-1 of bwd: uniform mean over all Vb keys ----------------
__global__ __launch_bounds__(256) void vmean_kernel(const short* __restrict__ VT,
                                                    short* __restrict__ bwd) {
  __shared__ float red[256];
  const int bh = blockIdx.x;  // b*NH + h
  const int d = threadIdx.x >> 2;
  const int seg = threadIdx.x & 3;
  const short* row = VT + (size_t)bh * S_LEN * HD + (size_t)d * S_LEN + seg * 512;
  float s = 0.f;
  for (int j = 0; j < 512; j += 8) {
    uint4 v = *reinterpret_cast<const uint4*>(row + j);
    s += bflo(v.x) + bfhi(v.x) + bflo(v.y) + bfhi(v.y) +
         bflo(v.z) + bfhi(v.z) + bflo(v.w) + bfhi(v.w);
  }
  red[threadIdx.x] = s;
  __syncthreads();
  if (seg == 0) {
    float t = red[d * 4] + red[d * 4 + 1] + red[d * 4 + 2] + red[d * 4 + 3];
    int b = bh >> 4, h = bh & 15;
    bwd[((size_t)(b * S_LEN + S_LEN - 1)) * DMODEL + h * HD + d] = f2bf(t * (1.f / S_LEN));
  }
}

// ---------------- gate LN + sigmoid + fuse (sums 2 partials) ----------------
__global__ __launch_bounds__(256) void ln_gate_fuse_kernel(
    const float* __restrict__ g0p, const float* __restrict__ g1p,
    const float* __restrict__ gln_g, const float* __restrict__ gln_b,
    const short* __restrict__ fwd, const short* __restrict__ bwd,
    const float* __restrict__ bstr, short* __restrict__ fused) {
  __shared__ float red[8];
  const int row = blockIdx.x;
  const int tid = threadIdx.x;
  const int lane = tid & 63;
  const int w = tid >> 6;
  float4 x0 = *reinterpret_cast<const float4*>(g0p + (size_t)row * DMODEL + tid * 4);
  float4 x1 = *reinterpret_cast<const float4*>(g1p + (size_t)row * DMODEL + tid * 4);
  float xa[4] = {x0.x + x1.x, x0.y + x1.y, x0.z + x1.z, x0.w + x1.w};
  float s = xa[0] + xa[1] + xa[2] + xa[3];
  float ss = xa[0] * xa[0] + xa[1] * xa[1] + xa[2] * xa[2] + xa[3] * xa[3];
  for (int off = 1; off < 64; off <<= 1) {
    s += __shfl_xor(s, off);
    ss += __shfl_xor(ss, off);
  }
  if (lane == 0) { red[w] = s; red[4 + w] = ss; }
  __syncthreads();
  s = red[0] + red[1] + red[2] + red[3];
  ss = red[4] + red[5] + red[6] + red[7];
  const float mean = s * (1.f / DMODEL);
  const float var = ss * (1.f / DMODEL) - mean * mean;
  const float rstd = rsqrtf(var + 1e-5f);
  const float strength = 0.3f / (1.f + __expf(-bstr[0]));
  for (int e = 0; e < 4; ++e) {
    int idx = tid * 4 + e;
    float g = (xa[e] - mean) * rstd * gln_g[idx] + gln_b[idx];
    float gate = 1.f / (1.f + __expf(-g));
    float f = bf2f(fwd[(size_t)row * DMODEL + idx]) +
              strength * gate * bf2f(bwd[(size_t)row * DMODEL + idx]);
    fused[(size_t)row * DMODEL + idx] = f2bf(f);
  }
}

// ---------------- final residual LN (sums 2 partials) ----------------
__global__ __launch_bounds__(256) void final_ln_kernel(const float* __restrict__ x,
                                                       const float* __restrict__ o0p,
                                                       const float* __restrict__ o1p,
                                                       const float* __restrict__ ln_g,
                                                       const float* __restrict__ ln_b,
                                                       float* __restrict__ y) {
  __shared__ float red[8];
  const int row = blockIdx.x;
  const int tid = threadIdx.x;
  const int lane = tid & 63;
  const int w = tid >> 6;
  float4 xv = *reinterpret_cast<const float4*>(x + (size_t)row * DMODEL + tid * 4);
  float4 o0 = *reinterpret_cast<const float4*>(o0p + (size_t)row * DMODEL + tid * 4);
  float4 o1 = *reinterpret_cast<const float4*>(o1p + (size_t)row * DMODEL + tid * 4);
  float t[4] = {xv.x + o0.x + o1.x, xv.y + o0.y + o1.y,
                xv.z + o0.z + o1.z, xv.w + o0.w + o1.w};
  float s = t[0] + t[1] + t[2] + t[3];
  float ss = t[0] * t[0] + t[1] * t[1] + t[2] * t[2] + t[3] * t[3];
  for (int off = 1; off < 64; off <<= 1) {
    s += __shfl_xor(s, off);
    ss += __shfl_xor(ss, off);
  }
  if (lane == 0) { red[w] = s; red[4 + w] = ss; }
  __syncthreads();
  s = red[0] + red[1] + red[2] + red[3];
  ss = red[4] + red[5] + red[6] + red[7];
  const float mean = s * (1.f / DMODEL);
  const float var = ss * (1.f / DMODEL) - mean * mean;
  const float rstd = rsqrtf(var + 1e-5f);
  for (int e = 0; e < 4; ++e) {
    int idx = tid * 4 + e;
    y[(size_t)row * DMODEL + idx] = (t[e] - mean) * rstd * ln_g[idx] + ln_b[idx];
  }
}

extern "C" void kernel_launch(void* const* d_in, const int* in_sizes, int n_in,
                              void* d_out, int out_size, void* d_ws, size_t ws_size,
                              hipStream_t stream) {
  const float* x = (const float*)d_in[0];
  const float* fq_w = (const float*)d_in[1];
  const float* fq_b = (const float*)d_in[2];
  const float* fk_w = (const float*)d_in[3];
  const float* fk_b = (const float*)d_in[4];
  const float* fv_w = (const float*)d_in[5];
  const float* fv_b = (const float*)d_in[6];
  const float* bq_w = (const float*)d_in[7];
  const float* bq_b = (const float*)d_in[8];
  const float* bk_w = (const float*)d_in[9];
  const float* bk_b = (const float*)d_in[10];
  const float* bv_w = (const float*)d_in[11];
  const float* bv_b = (const float*)d_in[12];
  const float* gate_w = (const float*)d_in[13];
  const float* gate_b = (const float*)d_in[14];
  const float* gln_g = (const float*)d_in[15];
  const float* gln_b = (const float*)d_in[16];
  const float* bstr = (const float*)d_in[17];
  const float* out_w = (const float*)d_in[18];
  const float* out_b = (const float*)d_in[19];
  const float* ln_g = (const float*)d_in[20];
  const float* ln_b = (const float*)d_in[21];

  char* ws = (char*)d_ws;
  const size_t MB = 1u << 20;
  short* xb = (short*)(ws + 0);
  short* wT0 = (short*)(ws + 8 * MB);
  short* wT1 = (short*)(ws + 10 * MB);
  short* wT2 = (short*)(ws + 12 * MB);
  short* wT3 = (short*)(ws + 14 * MB);
  short* wT4 = (short*)(ws + 16 * MB);
  short* wT5 = (short*)(ws + 18 * MB);
  short* gwT = (short*)(ws + 20 * MB);
  short* owT = (short*)(ws + 24 * MB);
  short* qkv = (short*)(ws + 26 * MB);      // 6 x 8 MB -> 26..74
  short* fwd = (short*)(ws + 0);            // over xb
  short* bwdb = (short*)(ws + 8 * MB);      // over wT0..3
  float* G0 = (float*)(ws + 26 * MB);       // over Q (dead after attn_fwd)
  float* G1 = (float*)(ws + 42 * MB);       // over V,Qb (dead)
  short* fused = (short*)(ws + 58 * MB);    // over Kb (dead)
  float* O0 = (float*)(ws + 26 * MB);       // over G0 (dead after ln_gate_fuse)
  float* O1 = (float*)(ws + 42 * MB);       // over G1 (dead)

  cvt_bf16_kernel<<<4096, 256, 0, stream>>>(x, xb, ELTS_PER);
  transpose_cvt_all<<<dim3(32, 64, 8), dim3(32, 8), 0, stream>>>(
      fq_w, fk_w, fv_w, bq_w, bk_w, bv_w, out_w, gate_w,
      wT0, wT1, wT2, wT3, wT4, wT5, owT, gwT);

  gemm_qkv_kernel<<<dim3(48, 32), 256, 0, stream>>>(
      xb, 1024, 1024, wT0, wT1, wT2, wT3, wT4, wT5,
      fq_b, fk_b, fv_b, bq_b, bk_b, bv_b, qkv);

  attn_fwd_kernel<<<512, 256, 0, stream>>>(
      qkv, qkv + (size_t)ELTS_PER, qkv + 2 * (size_t)ELTS_PER, fwd);
  attn_bwd_kernel<<<dim3(16, 16, 2), 256, 0, stream>>>(
      qkv + 3 * (size_t)ELTS_PER, qkv + 4 * (size_t)ELTS_PER, qkv + 5 * (size_t)ELTS_PER, bwdb);
  vmean_kernel<<<32, 256, 0, stream>>>(qkv + 5 * (size_t)ELTS_PER, bwdb);

  // gate GEMM: [4096,2048]@gate_w, K-split on the fwd/bwd concat boundary
  gemm_ksplit_kernel<<<dim3(8, 32, 2), 256, 0, stream>>>(
      fwd, bwdb, 1024, gwT, 2048, 1024, gate_b, G0, G1);

  ln_gate_fuse_kernel<<<4096, 256, 0, stream>>>(G0, G1, gln_g, gln_b, fwd, bwdb, bstr, fused);

  // out GEMM: [4096,1024]@out_w, K-split 512/512
  gemm_ksplit_kernel<<<dim3(8, 32, 2), 256, 0, stream>>>(
      fused, fused + 512, 1024, owT, 1024, 512, out_b, O0, O1);

  final_ln_kernel<<<4096, 256, 0, stream>>>(x, O0, O1, ln_g, ln_b, (float*)d_out);
}

// Round 8
// 264.045 us; speedup vs baseline: 1.9962x; 1.0480x over previous
//
#include <hip/hip_runtime.h>

#define S_LEN 2048
#define NH 16
#define HD 64
#define DMODEL 1024
#define NTOK 4096
#define ELTS_PER 4194304  // B*S*D = NTOK*DMODEL
#define QSCALE 0.18033688f  // 0.125 * log2(e), folded into Q/Qb projections

typedef __attribute__((ext_vector_type(8))) __bf16 bfrag;
typedef __attribute__((ext_vector_type(8))) short s8v;
typedef __attribute__((ext_vector_type(4))) float f32x4;

__device__ inline float bf2f(short s) {
  unsigned int u = ((unsigned int)(unsigned short)s) << 16;
  float f;
  __builtin_memcpy(&f, &u, 4);
  return f;
}
__device__ inline short f2bf(float f) {
  unsigned int u;
  __builtin_memcpy(&u, &f, 4);
  u = (u + 0x7fffu + ((u >> 16) & 1u)) >> 16;
  return (short)u;
}
__device__ inline short f2bf_n(float f) {  // native convert (packed cvt)
  __bf16 h = (__bf16)f;
  short s;
  __builtin_memcpy(&s, &h, 2);
  return s;
}
__device__ inline float bflo(unsigned int u) {
  unsigned int t = u << 16;
  float f; __builtin_memcpy(&f, &t, 4); return f;
}
__device__ inline float bfhi(unsigned int u) {
  unsigned int t = u & 0xffff0000u;
  float f; __builtin_memcpy(&f, &t, 4); return f;
}
// async global -> LDS, 16B per lane (dest = wave-uniform base + lane*16)
__device__ __forceinline__ void gll16(const short* g, short* l) {
  __builtin_amdgcn_global_load_lds(
      (const __attribute__((address_space(1))) void*)g,
      (__attribute__((address_space(3))) void*)l, 16, 0, 0);
}

// ---------------- convert x: f32 -> bf16 ----------------
__global__ __launch_bounds__(256) void cvt_bf16_kernel(const float* __restrict__ in,
                                                       short* __restrict__ out, int n) {
  int i = (blockIdx.x * 256 + threadIdx.x) * 4;
  if (i + 3 < n) {
    float4 v = *reinterpret_cast<const float4*>(in + i);
    short4 o;
    o.x = f2bf(v.x); o.y = f2bf(v.y); o.z = f2bf(v.z); o.w = f2bf(v.w);
    *reinterpret_cast<short4*>(out + i) = o;
  }
}

// ---------- transpose + convert ALL weights: f32 [K][N=1024] -> bf16 [N][K] ----------
__global__ void transpose_cvt_all(const float* __restrict__ s0, const float* __restrict__ s1,
                                  const float* __restrict__ s2, const float* __restrict__ s3,
                                  const float* __restrict__ s4, const float* __restrict__ s5,
                                  const float* __restrict__ s6, const float* __restrict__ s7,
                                  short* d0, short* d1, short* d2, short* d3,
                                  short* d4, short* d5, short* d6, short* d7) {
  const int z = blockIdx.z;
  const int K = (z == 7) ? 2048 : 1024;
  if (blockIdx.y * 32 >= K) return;
  const float* srcs[8] = {s0, s1, s2, s3, s4, s5, s6, s7};
  short* dsts[8] = {d0, d1, d2, d3, d4, d5, d6, d7};
  const float* in = srcs[z];
  short* out = dsts[z];
  __shared__ float tile[32][33];
  int nb = blockIdx.x * 32, kb = blockIdx.y * 32;
  int tx = threadIdx.x, ty = threadIdx.y;  // block (32,8)
  for (int j = 0; j < 32; j += 8)
    tile[ty + j][tx] = in[(size_t)(kb + ty + j) * 1024 + nb + tx];
  __syncthreads();
  for (int j = 0; j < 32; j += 8)
    out[(size_t)(nb + ty + j) * K + kb + tx] = f2bf(tile[tx][ty + j]);
}

// ---------------- QKV GEMM: BK=64, 3-bit XOR swizzle, LDS-staged epilogue ----------
// LDS[row][chunk c] = global[row][chunk c ^ (row&7)]; gll16 source pre-swizzled
// (lane l fetches chunk (l&7)^((l>>3)&7)); reads XOR the same -> conflict-free.
// Epilogue: C tile staged in LDS [128][136] bf16 (transposed for V/Vb), then
// 16B coalesced stores. NOTE: s-location within batch = m0 & 2047 (bb carries batch).
__global__ __launch_bounds__(256) void gemm_qkv_kernel(
    const short* __restrict__ A, int lda, int K,
    const short* __restrict__ B0, const short* __restrict__ B1, const short* __restrict__ B2,
    const short* __restrict__ B3, const short* __restrict__ B4, const short* __restrict__ B5,
    const float* __restrict__ bias0, const float* __restrict__ bias1,
    const float* __restrict__ bias2, const float* __restrict__ bias3,
    const float* __restrict__ bias4, const float* __restrict__ bias5,
    short* __restrict__ outQ) {
  __shared__ short lds[128 * 136];  // 34.8 KB: K-loop uses [0,16384); epilogue all
  short* As = lds;                  // 128 x 64
  short* Bs = lds + 8192;           // 128 x 64
  const int tid = threadIdx.x;
  const int n0 = blockIdx.x * 128;
  const int m0 = blockIdx.y * 128;
  const short* Bp[6] = {B0, B1, B2, B3, B4, B5};
  const float* biasP[6] = {bias0, bias1, bias2, bias3, bias4, bias5};
  const int nsel = n0 >> 10;
  const int nc0 = n0 & 1023;
  const short* Bt = Bp[nsel] + (size_t)nc0 * K;
  const float* bsel = biasP[nsel];

  const int lane = tid & 63;
  const int w = tid >> 6;
  const int wm = (w >> 1) * 64;
  const int wn = (w & 1) * 64;
  const int lr = lane & 15;
  const int lg = lane >> 4;
  const int rl = lane >> 3;                  // staging: row within 8-row round
  const int gch = (lane & 7) ^ (rl & 7);     // staging: pre-swizzled source chunk

  f32x4 acc[4][4];
  for (int a = 0; a < 4; ++a)
    for (int b = 0; b < 4; ++b) acc[a][b] = {0.f, 0.f, 0.f, 0.f};

  for (int k0 = 0; k0 < K; k0 += 64) {
    __syncthreads();
    for (int p = 0; p < 4; ++p) {
      int rb = (p * 4 + w) * 8;
      gll16(A + (size_t)(m0 + rb + rl) * lda + k0 + gch * 8, &As[rb * 64]);
      gll16(Bt + (size_t)(rb + rl) * K + k0 + gch * 8, &Bs[rb * 64]);
    }
    __syncthreads();
    for (int ks = 0; ks < 2; ++ks) {
      bfrag af[4], bf[4];
      for (int t = 0; t < 4; ++t) {
        af[t] = *reinterpret_cast<const bfrag*>(
            &As[(wm + t * 16 + lr) * 64 + (((lg + 4 * ks) ^ (lr & 7)) * 8)]);
        bf[t] = *reinterpret_cast<const bfrag*>(
            &Bs[(wn + t * 16 + lr) * 64 + (((lg + 4 * ks) ^ (lr & 7)) * 8)]);
      }
      for (int mt = 0; mt < 4; ++mt)
        for (int nt = 0; nt < 4; ++nt)
          acc[mt][nt] = __builtin_amdgcn_mfma_f32_16x16x32_bf16(af[mt], bf[nt], acc[mt][nt], 0, 0, 0);
    }
  }

  // ---- epilogue: stage C in LDS (bf16), then coalesced 16B stores ----
  const float cmul = (nsel == 0 || nsel == 3) ? QSCALE : 1.0f;
  const bool tr = (nsel == 2 || nsel == 5);
  __syncthreads();  // all LDS frag reads done; safe to overwrite
  for (int mt = 0; mt < 4; ++mt)
    for (int nt = 0; nt < 4; ++nt) {
      int c = wn + nt * 16 + lr;
      float bv = bsel[nc0 + c];
      for (int i = 0; i < 4; ++i) {
        int r = wm + mt * 16 + lg * 4 + i;
        short v16 = f2bf_n((acc[mt][nt][i] + bv) * cmul);
        if (tr) lds[c * 136 + r] = v16;
        else lds[r * 136 + c] = v16;
      }
    }
  __syncthreads();
  const int bb = m0 >> 11;
  const int sloc = m0 & 2047;   // s-offset within the batch (FIX: was m0)
  const int hh0 = nc0 >> 6;
  short* basebuf = outQ + (size_t)nsel * ELTS_PER;
  for (int j = 0; j < 8; ++j) {
    int gid = j * 256 + tid;
    int rr = gid >> 4;     // 0..127
    int ch = gid & 15;     // 16B chunk
    s8v v = *reinterpret_cast<const s8v*>(&lds[rr * 136 + ch * 8]);
    if (tr) {
      // lds row rr = output d-index; chunks along s
      int hh = hh0 + (rr >> 6), d = rr & 63;
      *reinterpret_cast<s8v*>(
          basebuf + ((size_t)(bb * NH + hh) * HD + d) * S_LEN + sloc + ch * 8) = v;
    } else {
      // lds row rr = token row; chunks along d (2 heads per tile)
      int hh = hh0 + (ch >> 3), d0 = (ch & 7) * 8;
      *reinterpret_cast<s8v*>(
          basebuf + ((size_t)(bb * NH + hh) * S_LEN + sloc + rr) * HD + d0) = v;
    }
  }
}

// ---------------- K-split GEMM (BK=64), f32 partial outputs ----------------
__global__ __launch_bounds__(256) void gemm_ksplit_kernel(
    const short* __restrict__ A0, const short* __restrict__ A1, int lda,
    const short* __restrict__ B, int ldb, int K,
    const float* __restrict__ bias, float* __restrict__ out0, float* __restrict__ out1) {
  __shared__ short lds[16384];
  short* As = lds;
  short* Bs = lds + 8192;
  const int tid = threadIdx.x;
  const int n0 = blockIdx.x * 128;
  const int m0 = blockIdx.y * 128;
  const int z = blockIdx.z;
  const short* A = z ? A1 : A0;
  const short* Bt = B + (size_t)n0 * ldb + z * K;
  float* outp = z ? out1 : out0;

  const int lane = tid & 63;
  const int w = tid >> 6;
  const int wm = (w >> 1) * 64;
  const int wn = (w & 1) * 64;
  const int lr = lane & 15;
  const int lg = lane >> 4;
  const int rl = lane >> 3;
  const int gch = (lane & 7) ^ (rl & 7);

  f32x4 acc[4][4];
  for (int a = 0; a < 4; ++a)
    for (int b = 0; b < 4; ++b) acc[a][b] = {0.f, 0.f, 0.f, 0.f};

  for (int k0 = 0; k0 < K; k0 += 64) {
    __syncthreads();
    for (int p = 0; p < 4; ++p) {
      int rb = (p * 4 + w) * 8;
      gll16(A + (size_t)(m0 + rb + rl) * lda + k0 + gch * 8, &As[rb * 64]);
      gll16(Bt + (size_t)(rb + rl) * ldb + k0 + gch * 8, &Bs[rb * 64]);
    }
    __syncthreads();
    for (int ks = 0; ks < 2; ++ks) {
      bfrag af[4], bf[4];
      for (int t = 0; t < 4; ++t) {
        af[t] = *reinterpret_cast<const bfrag*>(
            &As[(wm + t * 16 + lr) * 64 + (((lg + 4 * ks) ^ (lr & 7)) * 8)]);
        bf[t] = *reinterpret_cast<const bfrag*>(
            &Bs[(wn + t * 16 + lr) * 64 + (((lg + 4 * ks) ^ (lr & 7)) * 8)]);
      }
      for (int mt = 0; mt < 4; ++mt)
        for (int nt = 0; nt < 4; ++nt)
          acc[mt][nt] = __builtin_amdgcn_mfma_f32_16x16x32_bf16(af[mt], bf[nt], acc[mt][nt], 0, 0, 0);
    }
  }

  for (int mt = 0; mt < 4; ++mt)
    for (int nt = 0; nt < 4; ++nt)
      for (int i = 0; i < 4; ++i) {
        int row = m0 + wm + mt * 16 + lg * 4 + i;
        int col = n0 + wn + nt * 16 + lr;
        float v = acc[mt][nt][i] + (z == 0 ? bias[col] : 0.f);
        outp[(size_t)row * DMODEL + col] = v;
      }
}

// ---------------- causal flash attention fwd (v4) ----------------
__global__ __launch_bounds__(256) void attn_fwd_kernel(const short* __restrict__ Q,
                                                       const short* __restrict__ Kk,
                                                       const short* __restrict__ VT,
                                                       short* __restrict__ fwd) {
  __shared__ short Ps[4][32 * 72];
  const int tid = threadIdx.x;
  const int lane = tid & 63;
  const int w = tid >> 6;
  const int lr = lane & 15;
  const int lg = lane >> 4;
  const int f = blockIdx.x;              // 0..511
  const int xcd = f & 7;
  const int slot = f >> 3;               // 0..63
  const int bh = xcd * 4 + (slot >> 4);  // 0..31
  const int p = slot & 15;
  const int b = bh >> 4;
  const int h = bh & 15;
  const size_t hb = (size_t)(b * NH + h) * S_LEN * HD;
  short* Pw = Ps[w];

  s8v onesi = {0x3F80, 0x3F80, 0x3F80, 0x3F80, 0x3F80, 0x3F80, 0x3F80, 0x3F80};
  bfrag onesv;
  __builtin_memcpy(&onesv, &onesi, 16);

  const int c = (w < 2) ? (2 * p + w) : (63 - 2 * p - (w - 2));
  const int q0 = c * 32;
  const int ktm = c >> 1;

  bfrag qf[2][2];
  for (int mt = 0; mt < 2; ++mt)
    for (int kc = 0; kc < 2; ++kc)
      qf[mt][kc] = *reinterpret_cast<const bfrag*>(
          Q + hb + (size_t)(q0 + mt * 16 + lr) * HD + kc * 32 + lg * 8);

  f32x4 oacc[2][4];
  for (int mt = 0; mt < 2; ++mt)
    for (int nd = 0; nd < 4; ++nd) oacc[mt][nd] = {0.f, 0.f, 0.f, 0.f};
  f32x4 osum[2];
  osum[0] = {0.f, 0.f, 0.f, 0.f};
  osum[1] = {0.f, 0.f, 0.f, 0.f};

  bfrag ka[4][2];
  for (int nb = 0; nb < 4; ++nb)
    for (int kc = 0; kc < 2; ++kc)
      ka[nb][kc] = *reinterpret_cast<const bfrag*>(
          Kk + hb + (size_t)(nb * 16 + lr) * HD + kc * 32 + lg * 8);

  for (int kt = 0; kt <= ktm; ++kt) {
    bfrag vf[4][2];
    for (int nd = 0; nd < 4; ++nd)
      for (int kc = 0; kc < 2; ++kc)
        vf[nd][kc] = *reinterpret_cast<const bfrag*>(
            VT + hb + (size_t)(nd * 16 + lr) * S_LEN + kt * 64 + kc * 32 + lg * 8);
    f32x4 sv[2][4];
    for (int mt = 0; mt < 2; ++mt)
      for (int nb = 0; nb < 4; ++nb) {
        f32x4 z = {0.f, 0.f, 0.f, 0.f};
        z = __builtin_amdgcn_mfma_f32_16x16x32_bf16(qf[mt][0], ka[nb][0], z, 0, 0, 0);
        sv[mt][nb] = __builtin_amdgcn_mfma_f32_16x16x32_bf16(qf[mt][1], ka[nb][1], z, 0, 0, 0);
      }
    if (kt < ktm) {
      for (int nb = 0; nb < 4; ++nb)
        for (int kc = 0; kc < 2; ++kc)
          ka[nb][kc] = *reinterpret_cast<const bfrag*>(
              Kk + hb + (size_t)((kt + 1) * 64 + nb * 16 + lr) * HD + kc * 32 + lg * 8);
    }
    if (kt == ktm) {
      for (int mt = 0; mt < 2; ++mt)
        for (int nb = 0; nb < 4; ++nb)
          for (int i = 0; i < 4; ++i) {
            int colg = kt * 64 + nb * 16 + lr;
            int rowg = q0 + mt * 16 + lg * 4 + i;
            if (colg > rowg) sv[mt][nb][i] = -1e30f;
          }
    }
    for (int mt = 0; mt < 2; ++mt)
      for (int nb = 0; nb < 4; ++nb)
        for (int i = 0; i < 4; ++i)
          Pw[(mt * 16 + lg * 4 + i) * 72 + nb * 16 + lr] = f2bf_n(exp2f(sv[mt][nb][i]));
    for (int mt = 0; mt < 2; ++mt) {
      bfrag pa0 = *reinterpret_cast<const bfrag*>(&Pw[(mt * 16 + lr) * 72 + lg * 8]);
      bfrag pa1 = *reinterpret_cast<const bfrag*>(&Pw[(mt * 16 + lr) * 72 + 32 + lg * 8]);
      for (int nd = 0; nd < 4; ++nd) {
        oacc[mt][nd] = __builtin_amdgcn_mfma_f32_16x16x32_bf16(pa0, vf[nd][0], oacc[mt][nd], 0, 0, 0);
        oacc[mt][nd] = __builtin_amdgcn_mfma_f32_16x16x32_bf16(pa1, vf[nd][1], oacc[mt][nd], 0, 0, 0);
      }
      osum[mt] = __builtin_amdgcn_mfma_f32_16x16x32_bf16(pa0, onesv, osum[mt], 0, 0, 0);
      osum[mt] = __builtin_amdgcn_mfma_f32_16x16x32_bf16(pa1, onesv, osum[mt], 0, 0, 0);
    }
  }

  for (int mt = 0; mt < 2; ++mt)
    for (int i = 0; i < 4; ++i) {
      int rowg = q0 + mt * 16 + lg * 4 + i;
      float inv = 1.0f / osum[mt][i];
      for (int nd = 0; nd < 4; ++nd)
        fwd[(size_t)(b * S_LEN + rowg) * DMODEL + h * HD + nd * 16 + lr] =
            f2bf(oacc[mt][nd][i] * inv);
    }
}

// ---------------- windowed backward attention (MFMA single-tile) ----------------
__global__ __launch_bounds__(256) void attn_bwd_kernel(const short* __restrict__ Qb,
                                                       const short* __restrict__ Kb,
                                                       const short* __restrict__ VT,
                                                       short* __restrict__ bwd) {
  __shared__ short Ps[4][32 * 72];
  const int tid = threadIdx.x;
  const int lane = tid & 63;
  const int w = tid >> 6;
  const int lr = lane & 15;
  const int lg = lane >> 4;
  const int h = blockIdx.y;
  const int b = blockIdx.z;
  const size_t hb = (size_t)(b * NH + h) * S_LEN * HD;
  const int q0 = blockIdx.x * 128 + w * 32;
  short* Pw = Ps[w];

  bfrag qf[2][2];
  for (int mt = 0; mt < 2; ++mt)
    for (int kc = 0; kc < 2; ++kc)
      qf[mt][kc] = *reinterpret_cast<const bfrag*>(
          Qb + hb + (size_t)(q0 + mt * 16 + lr) * HD + kc * 32 + lg * 8);
  bfrag kf[4][2];
  for (int nb = 0; nb < 4; ++nb) {
    int kr = q0 + nb * 16 + lr;
    kr = min(kr, S_LEN - 1);
    for (int kc = 0; kc < 2; ++kc)
      kf[nb][kc] = *reinterpret_cast<const bfrag*>(
          Kb + hb + (size_t)kr * HD + kc * 32 + lg * 8);
  }
  f32x4 sv[2][4];
  for (int mt = 0; mt < 2; ++mt)
    for (int nb = 0; nb < 4; ++nb) {
      f32x4 z = {0.f, 0.f, 0.f, 0.f};
      z = __builtin_amdgcn_mfma_f32_16x16x32_bf16(qf[mt][0], kf[nb][0], z, 0, 0, 0);
      sv[mt][nb] = __builtin_amdgcn_mfma_f32_16x16x32_bf16(qf[mt][1], kf[nb][1], z, 0, 0, 0);
    }
  float mx[2][4];
  for (int mt = 0; mt < 2; ++mt)
    for (int i = 0; i < 4; ++i) {
      int rowg = q0 + mt * 16 + lg * 4 + i;
      float m = -1e30f;
      for (int nb = 0; nb < 4; ++nb) {
        int colg = q0 + nb * 16 + lr;
        float t = sv[mt][nb][i];
        bool valid = (colg > rowg) && (colg <= rowg + 32) && (colg < S_LEN);
        if (!valid) t = -1e30f;
        sv[mt][nb][i] = t;
        m = fmaxf(m, t);
      }
      mx[mt][i] = m;
    }
  for (int off = 1; off < 16; off <<= 1)
    for (int mt = 0; mt < 2; ++mt)
      for (int i = 0; i < 4; ++i) mx[mt][i] = fmaxf(mx[mt][i], __shfl_xor(mx[mt][i], off));
  float rs[2][4] = {{0.f, 0.f, 0.f, 0.f}, {0.f, 0.f, 0.f, 0.f}};
  for (int mt = 0; mt < 2; ++mt)
    for (int nb = 0; nb < 4; ++nb)
      for (int i = 0; i < 4; ++i) {
        float p = exp2f(sv[mt][nb][i] - mx[mt][i]);
        rs[mt][i] += p;
        Pw[(mt * 16 + lg * 4 + i) * 72 + nb * 16 + lr] = f2bf_n(p);
      }
  for (int off = 1; off < 16; off <<= 1)
    for (int mt = 0; mt < 2; ++mt)
      for (int i = 0; i < 4; ++i) rs[mt][i] += __shfl_xor(rs[mt][i], off);
  bfrag vf[4][2];
  for (int nd = 0; nd < 4; ++nd)
    for (int kc = 0; kc < 2; ++kc) {
      int sbase = q0 + kc * 32 + lg * 8;
      sbase = min(sbase, S_LEN - 8);
      vf[nd][kc] = *reinterpret_cast<const bfrag*>(
          VT + hb + (size_t)(nd * 16 + lr) * S_LEN + sbase);
    }
  f32x4 oacc[2][4];
  for (int mt = 0; mt < 2; ++mt)
    for (int nd = 0; nd < 4; ++nd) oacc[mt][nd] = {0.f, 0.f, 0.f, 0.f};
  for (int mt = 0; mt < 2; ++mt) {
    bfrag pa0 = *reinterpret_cast<const bfrag*>(&Pw[(mt * 16 + lr) * 72 + lg * 8]);
    bfrag pa1 = *reinterpret_cast<const bfrag*>(&Pw[(mt * 16 + lr) * 72 + 32 + lg * 8]);
    for (int nd = 0; nd < 4; ++nd) {
      oacc[mt][nd] = __builtin_amdgcn_mfma_f32_16x16x32_bf16(pa0, vf[nd][0], oacc[mt][nd], 0, 0, 0);
      oacc[mt][nd] = __builtin_amdgcn_mfma_f32_16x16x32_bf16(pa1, vf[nd][1], oacc[mt][nd], 0, 0, 0);
    }
  }
  for (int mt = 0; mt < 2; ++mt)
    for (int nd = 0; nd < 4; ++nd)
      for (int i = 0; i < 4; ++i) {
        int rowg = q0 + mt * 16 + lg * 4 + i;
        float ov = oacc[mt][nd][i] / rs[mt][i];
        bwd[(size_t)(b * S_LEN + rowg) * DMODEL + h * HD + nd * 16 + lr] = f2bf(ov);
      }
}

// ---------------- row S-1 of bwd: uniform mean over all Vb keys ----------------
__global__ __launch_bounds__(256) void vmean_kernel(const short* __restrict__ VT,
                                                    short* __restrict__ bwd) {
  __shared__ float red[256];
  const int bh = blockIdx.x;  // b*NH + h
  const int d = threadIdx.x >> 2;
  const int seg = threadIdx.x & 3;
  const short* row = VT + (size_t)bh * S_LEN * HD + (size_t)d * S_LEN + seg * 512;
  float s = 0.f;
  for (int j = 0; j < 512; j += 8) {
    uint4 v = *reinterpret_cast<const uint4*>(row + j);
    s += bflo(v.x) + bfhi(v.x) + bflo(v.y) + bfhi(v.y) +
         bflo(v.z) + bfhi(v.z) + bflo(v.w) + bfhi(v.w);
  }
  red[threadIdx.x] = s;
  __syncthreads();
  if (seg == 0) {
    float t = red[d * 4] + red[d * 4 + 1] + red[d * 4 + 2] + red[d * 4 + 3];
    int b = bh >> 4, h = bh & 15;
    bwd[((size_t)(b * S_LEN + S_LEN - 1)) * DMODEL + h * HD + d] = f2bf(t * (1.f / S_LEN));
  }
}

// ---------------- gate LN + sigmoid + fuse (sums 2 partials) ----------------
__global__ __launch_bounds__(256) void ln_gate_fuse_kernel(
    const float* __restrict__ g0p, const float* __restrict__ g1p,
    const float* __restrict__ gln_g, const float* __restrict__ gln_b,
    const short* __restrict__ fwd, const short* __restrict__ bwd,
    const float* __restrict__ bstr, short* __restrict__ fused) {
  __shared__ float red[8];
  const int row = blockIdx.x;
  const int tid = threadIdx.x;
  const int lane = tid & 63;
  const int w = tid >> 6;
  float4 x0 = *reinterpret_cast<const float4*>(g0p + (size_t)row * DMODEL + tid * 4);
  float4 x1 = *reinterpret_cast<const float4*>(g1p + (size_t)row * DMODEL + tid * 4);
  float xa[4] = {x0.x + x1.x, x0.y + x1.y, x0.z + x1.z, x0.w + x1.w};
  float s = xa[0] + xa[1] + xa[2] + xa[3];
  float ss = xa[0] * xa[0] + xa[1] * xa[1] + xa[2] * xa[2] + xa[3] * xa[3];
  for (int off = 1; off < 64; off <<= 1) {
    s += __shfl_xor(s, off);
    ss += __shfl_xor(ss, off);
  }
  if (lane == 0) { red[w] = s; red[4 + w] = ss; }
  __syncthreads();
  s = red[0] + red[1] + red[2] + red[3];
  ss = red[4] + red[5] + red[6] + red[7];
  const float mean = s * (1.f / DMODEL);
  const float var = ss * (1.f / DMODEL) - mean * mean;
  const float rstd = rsqrtf(var + 1e-5f);
  const float strength = 0.3f / (1.f + __expf(-bstr[0]));
  for (int e = 0; e < 4; ++e) {
    int idx = tid * 4 + e;
    float g = (xa[e] - mean) * rstd * gln_g[idx] + gln_b[idx];
    float gate = 1.f / (1.f + __expf(-g));
    float f = bf2f(fwd[(size_t)row * DMODEL + idx]) +
              strength * gate * bf2f(bwd[(size_t)row * DMODEL + idx]);
    fused[(size_t)row * DMODEL + idx] = f2bf(f);
  }
}

// ---------------- final residual LN (sums 2 partials) ----------------
__global__ __launch_bounds__(256) void final_ln_kernel(const float* __restrict__ x,
                                                       const float* __restrict__ o0p,
                                                       const float* __restrict__ o1p,
                                                       const float* __restrict__ ln_g,
                                                       const float* __restrict__ ln_b,
                                                       float* __restrict__ y) {
  __shared__ float red[8];
  const int row = blockIdx.x;
  const int tid = threadIdx.x;
  const int lane = tid & 63;
  const int w = tid >> 6;
  float4 xv = *reinterpret_cast<const float4*>(x + (size_t)row * DMODEL + tid * 4);
  float4 o0 = *reinterpret_cast<const float4*>(o0p + (size_t)row * DMODEL + tid * 4);
  float4 o1 = *reinterpret_cast<const float4*>(o1p + (size_t)row * DMODEL + tid * 4);
  float t[4] = {xv.x + o0.x + o1.x, xv.y + o0.y + o1.y,
                xv.z + o0.z + o1.z, xv.w + o0.w + o1.w};
  float s = t[0] + t[1] + t[2] + t[3];
  float ss = t[0] * t[0] + t[1] * t[1] + t[2] * t[2] + t[3] * t[3];
  for (int off = 1; off < 64; off <<= 1) {
    s += __shfl_xor(s, off);
    ss += __shfl_xor(ss, off);
  }
  if (lane == 0) { red[w] = s; red[4 + w] = ss; }
  __syncthreads();
  s = red[0] + red[1] + red[2] + red[3];
  ss = red[4] + red[5] + red[6] + red[7];
  const float mean = s * (1.f / DMODEL);
  const float var = ss * (1.f / DMODEL) - mean * mean;
  const float rstd = rsqrtf(var + 1e-5f);
  for (int e = 0; e < 4; ++e) {
    int idx = tid * 4 + e;
    y[(size_t)row * DMODEL + idx] = (t[e] - mean) * rstd * ln_g[idx] + ln_b[idx];
  }
}

extern "C" void kernel_launch(void* const* d_in, const int* in_sizes, int n_in,
                              void* d_out, int out_size, void* d_ws, size_t ws_size,
                              hipStream_t stream) {
  const float* x = (const float*)d_in[0];
  const float* fq_w = (const float*)d_in[1];
  const float* fq_b = (const float*)d_in[2];
  const float* fk_w = (const float*)d_in[3];
  const float* fk_b = (const float*)d_in[4];
  const float* fv_w = (const float*)d_in[5];
  const float* fv_b = (const float*)d_in[6];
  const float* bq_w = (const float*)d_in[7];
  const float* bq_b = (const float*)d_in[8];
  const float* bk_w = (const float*)d_in[9];
  const float* bk_b = (const float*)d_in[10];
  const float* bv_w = (const float*)d_in[11];
  const float* bv_b = (const float*)d_in[12];
  const float* gate_w = (const float*)d_in[13];
  const float* gate_b = (const float*)d_in[14];
  const float* gln_g = (const float*)d_in[15];
  const float* gln_b = (const float*)d_in[16];
  const float* bstr = (const float*)d_in[17];
  const float* out_w = (const float*)d_in[18];
  const float* out_b = (const float*)d_in[19];
  const float* ln_g = (const float*)d_in[20];
  const float* ln_b = (const float*)d_in[21];

  char* ws = (char*)d_ws;
  const size_t MB = 1u << 20;
  short* xb = (short*)(ws + 0);
  short* wT0 = (short*)(ws + 8 * MB);
  short* wT1 = (short*)(ws + 10 * MB);
  short* wT2 = (short*)(ws + 12 * MB);
  short* wT3 = (short*)(ws + 14 * MB);
  short* wT4 = (short*)(ws + 16 * MB);
  short* wT5 = (short*)(ws + 18 * MB);
  short* gwT = (short*)(ws + 20 * MB);
  short* owT = (short*)(ws + 24 * MB);
  short* qkv = (short*)(ws + 26 * MB);      // 6 x 8 MB -> 26..74
  short* fwd = (short*)(ws + 0);            // over xb
  short* bwdb = (short*)(ws + 8 * MB);      // over wT0..3
  float* G0 = (float*)(ws + 26 * MB);       // over Q (dead after attn_fwd)
  float* G1 = (float*)(ws + 42 * MB);       // over V,Qb (dead)
  short* fused = (short*)(ws + 58 * MB);    // over Kb (dead)
  float* O0 = (float*)(ws + 26 * MB);       // over G0 (dead after ln_gate_fuse)
  float* O1 = (float*)(ws + 42 * MB);       // over G1 (dead)

  cvt_bf16_kernel<<<4096, 256, 0, stream>>>(x, xb, ELTS_PER);
  transpose_cvt_all<<<dim3(32, 64, 8), dim3(32, 8), 0, stream>>>(
      fq_w, fk_w, fv_w, bq_w, bk_w, bv_w, out_w, gate_w,
      wT0, wT1, wT2, wT3, wT4, wT5, owT, gwT);

  gemm_qkv_kernel<<<dim3(48, 32), 256, 0, stream>>>(
      xb, 1024, 1024, wT0, wT1, wT2, wT3, wT4, wT5,
      fq_b, fk_b, fv_b, bq_b, bk_b, bv_b, qkv);

  attn_fwd_kernel<<<512, 256, 0, stream>>>(
      qkv, qkv + (size_t)ELTS_PER, qkv + 2 * (size_t)ELTS_PER, fwd);
  attn_bwd_kernel<<<dim3(16, 16, 2), 256, 0, stream>>>(
      qkv + 3 * (size_t)ELTS_PER, qkv + 4 * (size_t)ELTS_PER, qkv + 5 * (size_t)ELTS_PER, bwdb);
  vmean_kernel<<<32, 256, 0, stream>>>(qkv + 5 * (size_t)ELTS_PER, bwdb);

  // gate GEMM: [4096,2048]@gate_w, K-split on the fwd/bwd concat boundary
  gemm_ksplit_kernel<<<dim3(8, 32, 2), 256, 0, stream>>>(
      fwd, bwdb, 1024, gwT, 2048, 1024, gate_b, G0, G1);

  ln_gate_fuse_kernel<<<4096, 256, 0, stream>>>(G0, G1, gln_g, gln_b, fwd, bwdb, bstr, fused);

  // out GEMM: [4096,1024]@out_w, K-split 512/512
  gemm_ksplit_kernel<<<dim3(8, 32, 2), 256, 0, stream>>>(
      fused, fused + 512, 1024, owT, 1024, 512, out_b, O0, O1);

  final_ln_kernel<<<4096, 256, 0, stream>>>(x, O0, O1, ln_g, ln_b, (float*)d_out);
}